// Round 6
// baseline (1010.493 us; speedup 1.0000x reference)
//
#include <hip/hip_runtime.h>
#include <hip/hip_fp16.h>

// GIN: 3 layers of {CSR-gather aggregate fused with (1+eps)*x, MLP(2x GEMM128 + BN + ReLU)},
// then lin1(128->128)+ReLU, lin2(128->10), log_softmax.
// N=100000, E=1.6M. Round 6: CSR build reworked as bucketed two-level sort
// (391 buckets of 256 nodes) -> scattered-4B-write amplification eliminated.

typedef _Float16 f16x8 __attribute__((ext_vector_type(8)));
typedef float f32x4 __attribute__((ext_vector_type(4)));

struct H4 { __half2 a, b; };   // 8B fp16 quad

// ---------------------------------------------------------------------------
// Detect whether edge_index is int64 (all high words zero) or int32.
__global__ void detect_idx_kernel(const unsigned int* __restrict__ w, long long nOdd,
                                  int* __restrict__ flag) {
    __shared__ int any;
    if (threadIdx.x == 0) any = 0;
    __syncthreads();
    for (long long i = threadIdx.x; i < nOdd; i += blockDim.x) {
        if (w[2 * i + 1] != 0u) { any = 1; break; }
    }
    __syncthreads();
    if (threadIdx.x == 0) *flag = (any == 0) ? 1 : 0;   // 1 => int64 layout
}

// ---------------------------------------------------------------------------
// Coarse histogram: bcnt[dst>>8] += 1, LDS pre-aggregated.
__global__ __launch_bounds__(256) void bucket_hist_kernel(
    const void* __restrict__ idx, long long E, const int* __restrict__ flag,
    int* __restrict__ bcnt, int NB) {
    __shared__ int h[512];
    for (int i = threadIdx.x; i < 512; i += 256) h[i] = 0;
    __syncthreads();
    long long i = (long long)blockIdx.x * blockDim.x + threadIdx.x;
    long long stride = (long long)gridDim.x * blockDim.x;
    if (*flag) {
        const long long* pd = (const long long*)idx + E;
        for (; i < E; i += stride) atomicAdd(&h[((int)pd[i]) >> 8], 1);
    } else {
        const int* pd = (const int*)idx + E;
        for (; i < E; i += stride) atomicAdd(&h[pd[i] >> 8], 1);
    }
    __syncthreads();
    for (int i = threadIdx.x; i < NB; i += 256) {
        int v = h[i];
        if (v) atomicAdd(&bcnt[i], v);
    }
}

// ---------------------------------------------------------------------------
// Exclusive scan of NB (<=512) bucket counts -> boff, bcur. row_ptr[N] = E.
__global__ __launch_bounds__(512) void bucket_scan_kernel(
    const int* __restrict__ bcnt, int* __restrict__ boff, int* __restrict__ bcur,
    int NB, int N, long long E, int* __restrict__ row_ptr) {
    int t = threadIdx.x;
    __shared__ int sh[512];
    int c = (t < NB) ? bcnt[t] : 0;
    sh[t] = c;
    __syncthreads();
    for (int off = 1; off < 512; off <<= 1) {
        int v = (t >= off) ? sh[t - off] : 0;
        __syncthreads();
        sh[t] += v;
        __syncthreads();
    }
    int excl = sh[t] - c;
    if (t < NB) { boff[t] = excl; bcur[t] = excl; }
    if (t == 0) { boff[NB] = (int)E; row_ptr[N] = (int)E; }
}

// ---------------------------------------------------------------------------
// Partition edges into bucket regions: bdata[bcur[dst>>8]++] = (src, dst).
// Only NB concurrent write heads -> lines fill densely -> L2 coalesces.
__global__ __launch_bounds__(256) void partition_kernel(
    const void* __restrict__ idx, long long E, const int* __restrict__ flag,
    int* __restrict__ bcur, uint2* __restrict__ bdata) {
    long long i = (long long)blockIdx.x * blockDim.x + threadIdx.x;
    long long stride = (long long)gridDim.x * blockDim.x;
    if (*flag) {
        const long long* ps = (const long long*)idx;
        const long long* pd = ps + E;
        for (; i < E; i += stride) {
            int s = (int)ps[i], d = (int)pd[i];
            int pos = atomicAdd(&bcur[d >> 8], 1);
            bdata[pos] = make_uint2((unsigned)s, (unsigned)d);
        }
    } else {
        const int* ps = (const int*)idx;
        const int* pd = ps + E;
        for (; i < E; i += stride) {
            int s = ps[i], d = pd[i];
            int pos = atomicAdd(&bcur[d >> 8], 1);
            bdata[pos] = make_uint2((unsigned)s, (unsigned)d);
        }
    }
}

// ---------------------------------------------------------------------------
// Per-bucket CSR finalize: LDS hist over 256 local nodes, LDS scan, row_ptr
// write, then place src into csr_src (16KB window per bucket, L2-absorbed).
__global__ __launch_bounds__(256) void csr_build_kernel(
    const uint2* __restrict__ bdata, const int* __restrict__ boff, int N,
    int* __restrict__ row_ptr, int* __restrict__ csr_src) {
    int b = blockIdx.x, t = threadIdx.x;
    int lo = boff[b], hi = boff[b + 1];
    int nb = b << 8;
    __shared__ int cnt[256];
    __shared__ int sh[256];
    cnt[t] = 0;
    __syncthreads();
    for (int i = lo + t; i < hi; i += 256)
        atomicAdd(&cnt[bdata[i].y & 255], 1);
    __syncthreads();
    int c = cnt[t];
    sh[t] = c;
    __syncthreads();
    for (int off = 1; off < 256; off <<= 1) {
        int v = (t >= off) ? sh[t - off] : 0;
        __syncthreads();
        sh[t] += v;
        __syncthreads();
    }
    int excl = sh[t] - c;
    if (nb + t < N) row_ptr[nb + t] = lo + excl;
    cnt[t] = excl;                 // cursor: local absolute position
    __syncthreads();
    for (int i = lo + t; i < hi; i += 256) {
        uint2 e = bdata[i];
        int p = atomicAdd(&cnt[e.y & 255], 1);
        csr_src[lo + p] = (int)e.x;
    }
}

// ---------------------------------------------------------------------------
// x fp32 [N,128] -> fp16. Each thread: 4 floats -> 4 halves (8B store).
__global__ void convert_x_kernel(__half* __restrict__ out, const float* __restrict__ in,
                                 int n4) {
    int i = blockIdx.x * blockDim.x + threadIdx.x;
    int stride = gridDim.x * blockDim.x;
    const float4* in4 = (const float4*)in;
    for (; i < n4; i += stride) {
        float4 v = in4[i];
        H4 h;
        h.a = __float22half2_rn(make_float2(v.x, v.y));
        h.b = __float22half2_rn(make_float2(v.z, v.w));
        *(H4*)(out + i * 4) = h;
    }
}

// ---------------------------------------------------------------------------
// Pack 7 fp32 [128][128] weight matrices (W1 l0..2, W2 l0..2, lin1) into fp16
// MFMA "A-operand" fragment order: pk[mat][((ks*8+ct)*64+lane)*8 + j] =
//   W[ks*32 + (lane>>4)*8 + j][ct*16 + (lane&15)]
__global__ void pack_w_kernel(__half* __restrict__ pk, const float* __restrict__ W1,
                              const float* __restrict__ W2, const float* __restrict__ lin1) {
    int t = blockIdx.x * blockDim.x + threadIdx.x;
    if (t >= 7 * 2048) return;
    int mat = t >> 11;
    int rem = t & 2047;
    int ks = rem >> 9;
    int ct = (rem >> 6) & 7;
    int lane = rem & 63;
    int g = lane >> 4, c = lane & 15;
    const float* src = (mat < 3) ? W1 + mat * 16384
                     : (mat < 6) ? W2 + (mat - 3) * 16384
                                 : lin1;
    __half* dst = pk + mat * 16384 + ((size_t)((ks * 8 + ct) * 64 + lane)) * 8;
#pragma unroll
    for (int j = 0; j < 8; ++j)
        dst[j] = (__half)src[(ks * 32 + g * 8 + j) * 128 + ct * 16 + c];
}

// ---------------------------------------------------------------------------
// out[n] = fp16( (1+eps)*x[n] + sum_j x[csr[j]] ), fp32 accumulate.
// One wave per node, half2 per lane, unroll x4.
__global__ __launch_bounds__(256) void gather_h_kernel(
    __half* __restrict__ out, const __half* __restrict__ x,
    const int* __restrict__ row_ptr, const int* __restrict__ csr,
    const float* __restrict__ eps, int layer, int N) {
    int wave = threadIdx.x >> 6;
    int lane = threadIdx.x & 63;
    int wid = blockIdx.x * 4 + wave;
    int nw = gridDim.x * 4;
    float s = 1.0f + eps[layer];
    for (int n = wid; n < N; n += nw) {
        float2 acc = __half22float2(((const __half2*)(x + n * 128))[lane]);
        acc.x *= s; acc.y *= s;
        int beg = row_ptr[n], end = row_ptr[n + 1];
        int j = beg;
        for (; j + 3 < end; j += 4) {
            int s0 = csr[j], s1 = csr[j + 1], s2 = csr[j + 2], s3 = csr[j + 3];
            float2 v0 = __half22float2(((const __half2*)(x + s0 * 128))[lane]);
            float2 v1 = __half22float2(((const __half2*)(x + s1 * 128))[lane]);
            float2 v2 = __half22float2(((const __half2*)(x + s2 * 128))[lane]);
            float2 v3 = __half22float2(((const __half2*)(x + s3 * 128))[lane]);
            acc.x += (v0.x + v1.x) + (v2.x + v3.x);
            acc.y += (v0.y + v1.y) + (v2.y + v3.y);
        }
        for (; j < end; ++j) {
            float2 v = __half22float2(((const __half2*)(x + csr[j] * 128))[lane]);
            acc.x += v.x;
            acc.y += v.y;
        }
        ((__half2*)(out + n * 128))[lane] = __float22half2_rn(acc);
    }
}

// ---------------------------------------------------------------------------
// out = relu(BN(in @ W + bias)) via MFMA f16. 128 rows/block, 256 thr (4 waves
// x 32 rows). A staged whole-K in LDS with XOR-swizzled 16B chunks; W read as
// pre-packed frags from global (L2-resident). Operands swapped (mfma(W,act))
// so each lane's C frag = 4 consecutive cols of one row -> 8B fp16 stores.
// g == nullptr: scale=1, shift=bias. In-place safe (block reads own rows only).
__global__ __launch_bounds__(256) void gemm_h_kernel(
    const __half* __restrict__ in, const __half* __restrict__ pk,
    const float* __restrict__ bias, const float* __restrict__ g,
    const float* __restrict__ bb, const float* __restrict__ m,
    const float* __restrict__ vv, __half* __restrict__ out, int N) {
    __shared__ __half sA[128 * 128];
    __shared__ float sc_s[128];
    __shared__ float sh_s[128];

    const int tid = threadIdx.x;
    if (tid < 128) {
        int c = tid;
        float sc, sh;
        if (g != nullptr) {
            sc = g[c] * rsqrtf(vv[c] + 1e-5f);
            sh = bias[c] * sc + bb[c] - m[c] * sc;
        } else {
            sc = 1.0f;
            sh = bias[c];
        }
        sc_s[c] = sc;
        sh_s[c] = sh;
    }

    const int base = blockIdx.x * 128;
    // stage 128 rows x 128 fp16 (16B chunks, chunk idx XOR row&15)
#pragma unroll
    for (int q = 0; q < 8; ++q) {
        int i = tid + q * 256;          // 0..2047 chunks
        int row = i >> 4, c = i & 15;
        int r = base + row;
        if (r >= N) r = N - 1;
        uint4 v = *(const uint4*)(in + r * 128 + c * 8);
        *(uint4*)&sA[row * 128 + ((c ^ (row & 15)) * 8)] = v;
    }
    __syncthreads();

    const int wave = tid >> 6;
    const int lane = tid & 63;
    const int g16 = lane >> 4;
    const int r15 = lane & 15;

    f32x4 acc[2][8];
#pragma unroll
    for (int rt = 0; rt < 2; ++rt)
#pragma unroll
        for (int ct = 0; ct < 8; ++ct) acc[rt][ct] = (f32x4)0.f;

#pragma unroll
    for (int ks = 0; ks < 4; ++ks) {
        f16x8 wf[8];
#pragma unroll
        for (int ct = 0; ct < 8; ++ct)
            wf[ct] = *(const f16x8*)(pk + ((ks * 8 + ct) * 64 + lane) * 8);
#pragma unroll
        for (int rt = 0; rt < 2; ++rt) {
            int row = wave * 32 + rt * 16 + r15;
            f16x8 bf = *(const f16x8*)&sA[row * 128 + (((ks * 4 + g16) ^ r15) * 8)];
#pragma unroll
            for (int ct = 0; ct < 8; ++ct)
                acc[rt][ct] = __builtin_amdgcn_mfma_f32_16x16x32_f16(wf[ct], bf,
                                                                     acc[rt][ct], 0, 0, 0);
        }
    }

    // epilogue: lane writes cols [ct*16+g16*4, +4) of row (base+wave*32+rt*16+r15)
#pragma unroll
    for (int rt = 0; rt < 2; ++rt) {
        int r = base + wave * 32 + rt * 16 + r15;
        if (r < N) {
            __half* orow = out + r * 128;
#pragma unroll
            for (int ct = 0; ct < 8; ++ct) {
                int col = ct * 16 + g16 * 4;
                float4 sc4 = *(float4*)&sc_s[col];
                float4 sh4 = *(float4*)&sh_s[col];
                f32x4 a = acc[rt][ct];
                float o0 = fmaxf(fmaf(a[0], sc4.x, sh4.x), 0.f);
                float o1 = fmaxf(fmaf(a[1], sc4.y, sh4.y), 0.f);
                float o2 = fmaxf(fmaf(a[2], sc4.z, sh4.z), 0.f);
                float o3 = fmaxf(fmaf(a[3], sc4.w, sh4.w), 0.f);
                H4 h;
                h.a = __float22half2_rn(make_float2(o0, o1));
                h.b = __float22half2_rn(make_float2(o2, o3));
                *(H4*)(orow + col) = h;
            }
        }
    }
}

// ---------------------------------------------------------------------------
// logits = in(fp16) @ W[128,10] + b; out = log_softmax (fp32). One row/wave.
__global__ __launch_bounds__(256) void head_kernel(
    const __half* __restrict__ in, const float* __restrict__ W,
    const float* __restrict__ b, float* __restrict__ out, int N) {
    __shared__ float Wl[128 * 10];
    __shared__ float bl[10];
    for (int i = threadIdx.x; i < 1280; i += blockDim.x) Wl[i] = W[i];
    if (threadIdx.x < 10) bl[threadIdx.x] = b[threadIdx.x];
    __syncthreads();
    int wave = threadIdx.x >> 6;
    int lane = threadIdx.x & 63;
    int wid = blockIdx.x * 4 + wave;
    int nw = gridDim.x * 4;
    for (int row = wid; row < N; row += nw) {
        float2 f = __half22float2(((const __half2*)(in + row * 128))[lane]);
        float logit[10];
#pragma unroll
        for (int c = 0; c < 10; ++c) {
            float p = f.x * Wl[(2 * lane) * 10 + c] + f.y * Wl[(2 * lane + 1) * 10 + c];
#pragma unroll
            for (int off = 32; off > 0; off >>= 1) p += __shfl_down(p, off);
            logit[c] = p;
        }
        if (lane == 0) {
            float mx = -1e30f;
#pragma unroll
            for (int c = 0; c < 10; ++c) {
                logit[c] += bl[c];
                mx = fmaxf(mx, logit[c]);
            }
            float sum = 0.f;
#pragma unroll
            for (int c = 0; c < 10; ++c) sum += expf(logit[c] - mx);
            float lse = mx + logf(sum);
            float* orow = out + (long long)row * 10;
#pragma unroll
            for (int c = 0; c < 10; ++c) orow[c] = logit[c] - lse;
        }
    }
}

// ---------------------------------------------------------------------------
extern "C" void kernel_launch(void* const* d_in, const int* in_sizes, int n_in,
                              void* d_out, int out_size, void* d_ws, size_t ws_size,
                              hipStream_t stream) {
    const float* x   = (const float*)d_in[0];
    const void*  eix = d_in[1];
    const float* eps = (const float*)d_in[2];
    const float* W1  = (const float*)d_in[3];
    const float* b1  = (const float*)d_in[4];
    const float* g1  = (const float*)d_in[5];
    const float* bb1 = (const float*)d_in[6];
    const float* m1  = (const float*)d_in[7];
    const float* v1  = (const float*)d_in[8];
    const float* W2  = (const float*)d_in[9];
    const float* b2  = (const float*)d_in[10];
    const float* g2  = (const float*)d_in[11];
    const float* bb2 = (const float*)d_in[12];
    const float* m2  = (const float*)d_in[13];
    const float* v2  = (const float*)d_in[14];
    const float* l1W = (const float*)d_in[15];
    const float* l1b = (const float*)d_in[16];
    const float* l2W = (const float*)d_in[17];
    const float* l2b = (const float*)d_in[18];

    const int N = in_sizes[0] / 128;
    const long long E = in_sizes[1] / 2;
    const int NB = (N + 255) >> 8;            // buckets of 256 nodes (<=512)

    // workspace layout (16B-aligned blocks first)
    __half* bufA  = (__half*)d_ws;                     // N*128 fp16
    __half* bufB  = bufA + (size_t)N * 128;            // N*128 fp16
    __half* pk    = bufB + (size_t)N * 128;            // 7*16384 fp16
    uint2*  bdata = (uint2*)(pk + 7 * 16384);          // E pairs (8B)
    int* csr_src  = (int*)(bdata + E);                 // E
    int* row_ptr  = csr_src + E;                       // N+1
    int* bcnt     = row_ptr + N + 1;                   // 512
    int* boff     = bcnt + 512;                        // 513
    int* bcur     = boff + 513;                        // 512
    int* flag     = bcur + 512;                        // 1

    detect_idx_kernel<<<1, 256, 0, stream>>>((const unsigned int*)eix,
                                             (E < 2048 ? E : 2048), flag);
    hipMemsetAsync(bcnt, 0, 512 * sizeof(int), stream);

    bucket_hist_kernel<<<256, 256, 0, stream>>>(eix, E, flag, bcnt, NB);
    bucket_scan_kernel<<<1, 512, 0, stream>>>(bcnt, boff, bcur, NB, N, E, row_ptr);
    partition_kernel<<<512, 256, 0, stream>>>(eix, E, flag, bcur, bdata);
    csr_build_kernel<<<NB, 256, 0, stream>>>(bdata, boff, N, row_ptr, csr_src);

    convert_x_kernel<<<2048, 256, 0, stream>>>(bufA, x, N * 32);
    pack_w_kernel<<<(7 * 2048 + 255) / 256, 256, 0, stream>>>(pk, W1, W2, l1W);

    const int gBlocks = 2048;
    const int mBlocks = (N + 127) / 128;

    __half* cur = bufA;
    __half* oth = bufB;
    for (int l = 0; l < 3; ++l) {
        gather_h_kernel<<<gBlocks, 256, 0, stream>>>(oth, cur, row_ptr, csr_src, eps, l, N);
        gemm_h_kernel<<<mBlocks, 256, 0, stream>>>(
            oth, pk + (size_t)l * 16384, b1 + l * 128, g1 + l * 128, bb1 + l * 128,
            m1 + l * 128, v1 + l * 128, oth, N);
        gemm_h_kernel<<<mBlocks, 256, 0, stream>>>(
            oth, pk + (size_t)(3 + l) * 16384, b2 + l * 128, g2 + l * 128, bb2 + l * 128,
            m2 + l * 128, v2 + l * 128, oth, N);
        __half* t = cur; cur = oth; oth = t;
    }
    // lin1 + ReLU (no BN)
    gemm_h_kernel<<<mBlocks, 256, 0, stream>>>(
        cur, pk + (size_t)6 * 16384, l1b, nullptr, nullptr, nullptr, nullptr, oth, N);
    // lin2 + log_softmax
    head_kernel<<<4096, 256, 0, stream>>>(oth, l2W, l2b, (float*)d_out, N);
}

// Round 7
// 540.076 us; speedup vs baseline: 1.8710x; 1.8710x over previous
//
#include <hip/hip_runtime.h>
#include <hip/hip_fp16.h>

// GIN: 3 layers of {CSR-gather aggregate fused with (1+eps)*x, MLP(2x GEMM128 + BN + ReLU)},
// then lin1(128->128)+ReLU, lin2(128->10), log_softmax.
// N=100000, E=1.6M. Round 7: bucket cursors padded to 128B each -- round 6's
// partition atomics serialized on 25 shared cache lines (555us); now 391 lines.

#define BPAD 32   // ints per bucket counter slot (128B -> one counter per line)

typedef _Float16 f16x8 __attribute__((ext_vector_type(8)));
typedef float f32x4 __attribute__((ext_vector_type(4)));

struct H4 { __half2 a, b; };   // 8B fp16 quad

// ---------------------------------------------------------------------------
// Detect whether edge_index is int64 (all high words zero) or int32.
__global__ void detect_idx_kernel(const unsigned int* __restrict__ w, long long nOdd,
                                  int* __restrict__ flag) {
    __shared__ int any;
    if (threadIdx.x == 0) any = 0;
    __syncthreads();
    for (long long i = threadIdx.x; i < nOdd; i += blockDim.x) {
        if (w[2 * i + 1] != 0u) { any = 1; break; }
    }
    __syncthreads();
    if (threadIdx.x == 0) *flag = (any == 0) ? 1 : 0;   // 1 => int64 layout
}

// ---------------------------------------------------------------------------
// Coarse histogram: bcnt[(dst>>8)*BPAD] += 1, LDS pre-aggregated.
__global__ __launch_bounds__(256) void bucket_hist_kernel(
    const void* __restrict__ idx, long long E, const int* __restrict__ flag,
    int* __restrict__ bcnt, int NB) {
    __shared__ int h[512];
    for (int i = threadIdx.x; i < 512; i += 256) h[i] = 0;
    __syncthreads();
    long long i = (long long)blockIdx.x * blockDim.x + threadIdx.x;
    long long stride = (long long)gridDim.x * blockDim.x;
    if (*flag) {
        const long long* pd = (const long long*)idx + E;
        for (; i < E; i += stride) atomicAdd(&h[((int)pd[i]) >> 8], 1);
    } else {
        const int* pd = (const int*)idx + E;
        for (; i < E; i += stride) atomicAdd(&h[pd[i] >> 8], 1);
    }
    __syncthreads();
    for (int i = threadIdx.x; i < NB; i += 256) {
        int v = h[i];
        if (v) atomicAdd(&bcnt[i * BPAD], v);
    }
}

// ---------------------------------------------------------------------------
// Exclusive scan of NB (<=512) bucket counts -> boff (compact), bcur (padded).
__global__ __launch_bounds__(512) void bucket_scan_kernel(
    const int* __restrict__ bcnt, int* __restrict__ boff, int* __restrict__ bcur,
    int NB, int N, long long E, int* __restrict__ row_ptr) {
    int t = threadIdx.x;
    __shared__ int sh[512];
    int c = (t < NB) ? bcnt[t * BPAD] : 0;
    sh[t] = c;
    __syncthreads();
    for (int off = 1; off < 512; off <<= 1) {
        int v = (t >= off) ? sh[t - off] : 0;
        __syncthreads();
        sh[t] += v;
        __syncthreads();
    }
    int excl = sh[t] - c;
    if (t < NB) { boff[t] = excl; bcur[t * BPAD] = excl; }
    if (t == 0) { boff[NB] = (int)E; row_ptr[N] = (int)E; }
}

// ---------------------------------------------------------------------------
// Partition edges into bucket regions: bdata[bcur[(dst>>8)*BPAD]++] = (src, dst).
__global__ __launch_bounds__(256) void partition_kernel(
    const void* __restrict__ idx, long long E, const int* __restrict__ flag,
    int* __restrict__ bcur, uint2* __restrict__ bdata) {
    long long i = (long long)blockIdx.x * blockDim.x + threadIdx.x;
    long long stride = (long long)gridDim.x * blockDim.x;
    if (*flag) {
        const long long* ps = (const long long*)idx;
        const long long* pd = ps + E;
        for (; i < E; i += stride) {
            int s = (int)ps[i], d = (int)pd[i];
            int pos = atomicAdd(&bcur[(d >> 8) * BPAD], 1);
            bdata[pos] = make_uint2((unsigned)s, (unsigned)d);
        }
    } else {
        const int* ps = (const int*)idx;
        const int* pd = ps + E;
        for (; i < E; i += stride) {
            int s = ps[i], d = pd[i];
            int pos = atomicAdd(&bcur[(d >> 8) * BPAD], 1);
            bdata[pos] = make_uint2((unsigned)s, (unsigned)d);
        }
    }
}

// ---------------------------------------------------------------------------
// Per-bucket CSR finalize: LDS hist over 256 local nodes, LDS scan, row_ptr
// write, then place src into csr_src (16KB window per bucket, L2-absorbed).
__global__ __launch_bounds__(256) void csr_build_kernel(
    const uint2* __restrict__ bdata, const int* __restrict__ boff, int N,
    int* __restrict__ row_ptr, int* __restrict__ csr_src) {
    int b = blockIdx.x, t = threadIdx.x;
    int lo = boff[b], hi = boff[b + 1];
    int nb = b << 8;
    __shared__ int cnt[256];
    __shared__ int sh[256];
    cnt[t] = 0;
    __syncthreads();
    for (int i = lo + t; i < hi; i += 256)
        atomicAdd(&cnt[bdata[i].y & 255], 1);
    __syncthreads();
    int c = cnt[t];
    sh[t] = c;
    __syncthreads();
    for (int off = 1; off < 256; off <<= 1) {
        int v = (t >= off) ? sh[t - off] : 0;
        __syncthreads();
        sh[t] += v;
        __syncthreads();
    }
    int excl = sh[t] - c;
    if (nb + t < N) row_ptr[nb + t] = lo + excl;
    cnt[t] = excl;                 // cursor: local absolute position
    __syncthreads();
    for (int i = lo + t; i < hi; i += 256) {
        uint2 e = bdata[i];
        int p = atomicAdd(&cnt[e.y & 255], 1);
        csr_src[lo + p] = (int)e.x;
    }
}

// ---------------------------------------------------------------------------
// x fp32 [N,128] -> fp16. Each thread: 4 floats -> 4 halves (8B store).
__global__ void convert_x_kernel(__half* __restrict__ out, const float* __restrict__ in,
                                 int n4) {
    int i = blockIdx.x * blockDim.x + threadIdx.x;
    int stride = gridDim.x * blockDim.x;
    const float4* in4 = (const float4*)in;
    for (; i < n4; i += stride) {
        float4 v = in4[i];
        H4 h;
        h.a = __float22half2_rn(make_float2(v.x, v.y));
        h.b = __float22half2_rn(make_float2(v.z, v.w));
        *(H4*)(out + i * 4) = h;
    }
}

// ---------------------------------------------------------------------------
// Pack 7 fp32 [128][128] weight matrices (W1 l0..2, W2 l0..2, lin1) into fp16
// MFMA "A-operand" fragment order: pk[mat][((ks*8+ct)*64+lane)*8 + j] =
//   W[ks*32 + (lane>>4)*8 + j][ct*16 + (lane&15)]
__global__ void pack_w_kernel(__half* __restrict__ pk, const float* __restrict__ W1,
                              const float* __restrict__ W2, const float* __restrict__ lin1) {
    int t = blockIdx.x * blockDim.x + threadIdx.x;
    if (t >= 7 * 2048) return;
    int mat = t >> 11;
    int rem = t & 2047;
    int ks = rem >> 9;
    int ct = (rem >> 6) & 7;
    int lane = rem & 63;
    int g = lane >> 4, c = lane & 15;
    const float* src = (mat < 3) ? W1 + mat * 16384
                     : (mat < 6) ? W2 + (mat - 3) * 16384
                                 : lin1;
    __half* dst = pk + mat * 16384 + ((size_t)((ks * 8 + ct) * 64 + lane)) * 8;
#pragma unroll
    for (int j = 0; j < 8; ++j)
        dst[j] = (__half)src[(ks * 32 + g * 8 + j) * 128 + ct * 16 + c];
}

// ---------------------------------------------------------------------------
// out[n] = fp16( (1+eps)*x[n] + sum_j x[csr[j]] ), fp32 accumulate.
// One wave per node, half2 per lane, unroll x4.
__global__ __launch_bounds__(256) void gather_h_kernel(
    __half* __restrict__ out, const __half* __restrict__ x,
    const int* __restrict__ row_ptr, const int* __restrict__ csr,
    const float* __restrict__ eps, int layer, int N) {
    int wave = threadIdx.x >> 6;
    int lane = threadIdx.x & 63;
    int wid = blockIdx.x * 4 + wave;
    int nw = gridDim.x * 4;
    float s = 1.0f + eps[layer];
    for (int n = wid; n < N; n += nw) {
        float2 acc = __half22float2(((const __half2*)(x + n * 128))[lane]);
        acc.x *= s; acc.y *= s;
        int beg = row_ptr[n], end = row_ptr[n + 1];
        int j = beg;
        for (; j + 3 < end; j += 4) {
            int s0 = csr[j], s1 = csr[j + 1], s2 = csr[j + 2], s3 = csr[j + 3];
            float2 v0 = __half22float2(((const __half2*)(x + s0 * 128))[lane]);
            float2 v1 = __half22float2(((const __half2*)(x + s1 * 128))[lane]);
            float2 v2 = __half22float2(((const __half2*)(x + s2 * 128))[lane]);
            float2 v3 = __half22float2(((const __half2*)(x + s3 * 128))[lane]);
            acc.x += (v0.x + v1.x) + (v2.x + v3.x);
            acc.y += (v0.y + v1.y) + (v2.y + v3.y);
        }
        for (; j < end; ++j) {
            float2 v = __half22float2(((const __half2*)(x + csr[j] * 128))[lane]);
            acc.x += v.x;
            acc.y += v.y;
        }
        ((__half2*)(out + n * 128))[lane] = __float22half2_rn(acc);
    }
}

// ---------------------------------------------------------------------------
// out = relu(BN(in @ W + bias)) via MFMA f16. 128 rows/block, 256 thr (4 waves
// x 32 rows). A staged whole-K in LDS with XOR-swizzled 16B chunks; W read as
// pre-packed frags from global (L2-resident). Operands swapped (mfma(W,act))
// so each lane's C frag = 4 consecutive cols of one row -> 8B fp16 stores.
// g == nullptr: scale=1, shift=bias. In-place safe (block reads own rows only).
__global__ __launch_bounds__(256) void gemm_h_kernel(
    const __half* __restrict__ in, const __half* __restrict__ pk,
    const float* __restrict__ bias, const float* __restrict__ g,
    const float* __restrict__ bb, const float* __restrict__ m,
    const float* __restrict__ vv, __half* __restrict__ out, int N) {
    __shared__ __half sA[128 * 128];
    __shared__ float sc_s[128];
    __shared__ float sh_s[128];

    const int tid = threadIdx.x;
    if (tid < 128) {
        int c = tid;
        float sc, sh;
        if (g != nullptr) {
            sc = g[c] * rsqrtf(vv[c] + 1e-5f);
            sh = bias[c] * sc + bb[c] - m[c] * sc;
        } else {
            sc = 1.0f;
            sh = bias[c];
        }
        sc_s[c] = sc;
        sh_s[c] = sh;
    }

    const int base = blockIdx.x * 128;
    // stage 128 rows x 128 fp16 (16B chunks, chunk idx XOR row&15)
#pragma unroll
    for (int q = 0; q < 8; ++q) {
        int i = tid + q * 256;          // 0..2047 chunks
        int row = i >> 4, c = i & 15;
        int r = base + row;
        if (r >= N) r = N - 1;
        uint4 v = *(const uint4*)(in + r * 128 + c * 8);
        *(uint4*)&sA[row * 128 + ((c ^ (row & 15)) * 8)] = v;
    }
    __syncthreads();

    const int wave = tid >> 6;
    const int lane = tid & 63;
    const int g16 = lane >> 4;
    const int r15 = lane & 15;

    f32x4 acc[2][8];
#pragma unroll
    for (int rt = 0; rt < 2; ++rt)
#pragma unroll
        for (int ct = 0; ct < 8; ++ct) acc[rt][ct] = (f32x4)0.f;

#pragma unroll
    for (int ks = 0; ks < 4; ++ks) {
        f16x8 wf[8];
#pragma unroll
        for (int ct = 0; ct < 8; ++ct)
            wf[ct] = *(const f16x8*)(pk + ((ks * 8 + ct) * 64 + lane) * 8);
#pragma unroll
        for (int rt = 0; rt < 2; ++rt) {
            int row = wave * 32 + rt * 16 + r15;
            f16x8 bf = *(const f16x8*)&sA[row * 128 + (((ks * 4 + g16) ^ r15) * 8)];
#pragma unroll
            for (int ct = 0; ct < 8; ++ct)
                acc[rt][ct] = __builtin_amdgcn_mfma_f32_16x16x32_f16(wf[ct], bf,
                                                                     acc[rt][ct], 0, 0, 0);
        }
    }

    // epilogue: lane writes cols [ct*16+g16*4, +4) of row (base+wave*32+rt*16+r15)
#pragma unroll
    for (int rt = 0; rt < 2; ++rt) {
        int r = base + wave * 32 + rt * 16 + r15;
        if (r < N) {
            __half* orow = out + r * 128;
#pragma unroll
            for (int ct = 0; ct < 8; ++ct) {
                int col = ct * 16 + g16 * 4;
                float4 sc4 = *(float4*)&sc_s[col];
                float4 sh4 = *(float4*)&sh_s[col];
                f32x4 a = acc[rt][ct];
                float o0 = fmaxf(fmaf(a[0], sc4.x, sh4.x), 0.f);
                float o1 = fmaxf(fmaf(a[1], sc4.y, sh4.y), 0.f);
                float o2 = fmaxf(fmaf(a[2], sc4.z, sh4.z), 0.f);
                float o3 = fmaxf(fmaf(a[3], sc4.w, sh4.w), 0.f);
                H4 h;
                h.a = __float22half2_rn(make_float2(o0, o1));
                h.b = __float22half2_rn(make_float2(o2, o3));
                *(H4*)(orow + col) = h;
            }
        }
    }
}

// ---------------------------------------------------------------------------
// logits = in(fp16) @ W[128,10] + b; out = log_softmax (fp32). One row/wave.
__global__ __launch_bounds__(256) void head_kernel(
    const __half* __restrict__ in, const float* __restrict__ W,
    const float* __restrict__ b, float* __restrict__ out, int N) {
    __shared__ float Wl[128 * 10];
    __shared__ float bl[10];
    for (int i = threadIdx.x; i < 1280; i += blockDim.x) Wl[i] = W[i];
    if (threadIdx.x < 10) bl[threadIdx.x] = b[threadIdx.x];
    __syncthreads();
    int wave = threadIdx.x >> 6;
    int lane = threadIdx.x & 63;
    int wid = blockIdx.x * 4 + wave;
    int nw = gridDim.x * 4;
    for (int row = wid; row < N; row += nw) {
        float2 f = __half22float2(((const __half2*)(in + row * 128))[lane]);
        float logit[10];
#pragma unroll
        for (int c = 0; c < 10; ++c) {
            float p = f.x * Wl[(2 * lane) * 10 + c] + f.y * Wl[(2 * lane + 1) * 10 + c];
#pragma unroll
            for (int off = 32; off > 0; off >>= 1) p += __shfl_down(p, off);
            logit[c] = p;
        }
        if (lane == 0) {
            float mx = -1e30f;
#pragma unroll
            for (int c = 0; c < 10; ++c) {
                logit[c] += bl[c];
                mx = fmaxf(mx, logit[c]);
            }
            float sum = 0.f;
#pragma unroll
            for (int c = 0; c < 10; ++c) sum += expf(logit[c] - mx);
            float lse = mx + logf(sum);
            float* orow = out + (long long)row * 10;
#pragma unroll
            for (int c = 0; c < 10; ++c) orow[c] = logit[c] - lse;
        }
    }
}

// ---------------------------------------------------------------------------
extern "C" void kernel_launch(void* const* d_in, const int* in_sizes, int n_in,
                              void* d_out, int out_size, void* d_ws, size_t ws_size,
                              hipStream_t stream) {
    const float* x   = (const float*)d_in[0];
    const void*  eix = d_in[1];
    const float* eps = (const float*)d_in[2];
    const float* W1  = (const float*)d_in[3];
    const float* b1  = (const float*)d_in[4];
    const float* g1  = (const float*)d_in[5];
    const float* bb1 = (const float*)d_in[6];
    const float* m1  = (const float*)d_in[7];
    const float* v1  = (const float*)d_in[8];
    const float* W2  = (const float*)d_in[9];
    const float* b2  = (const float*)d_in[10];
    const float* g2  = (const float*)d_in[11];
    const float* bb2 = (const float*)d_in[12];
    const float* m2  = (const float*)d_in[13];
    const float* v2  = (const float*)d_in[14];
    const float* l1W = (const float*)d_in[15];
    const float* l1b = (const float*)d_in[16];
    const float* l2W = (const float*)d_in[17];
    const float* l2b = (const float*)d_in[18];

    const int N = in_sizes[0] / 128;
    const long long E = in_sizes[1] / 2;
    const int NB = (N + 255) >> 8;            // buckets of 256 nodes (<=512)

    // workspace layout (16B-aligned blocks first)
    __half* bufA  = (__half*)d_ws;                     // N*128 fp16
    __half* bufB  = bufA + (size_t)N * 128;            // N*128 fp16
    __half* pk    = bufB + (size_t)N * 128;            // 7*16384 fp16
    uint2*  bdata = (uint2*)(pk + 7 * 16384);          // E pairs (8B)
    int* csr_src  = (int*)(bdata + E);                 // E
    int* row_ptr  = csr_src + E;                       // N+1
    int* bcnt     = row_ptr + N + 1;                   // 512*BPAD (padded)
    int* bcur     = bcnt + 512 * BPAD;                 // 512*BPAD (padded)
    int* boff     = bcur + 512 * BPAD;                 // 513
    int* flag     = boff + 513;                        // 1

    detect_idx_kernel<<<1, 256, 0, stream>>>((const unsigned int*)eix,
                                             (E < 2048 ? E : 2048), flag);
    hipMemsetAsync(bcnt, 0, (size_t)512 * BPAD * sizeof(int), stream);

    bucket_hist_kernel<<<256, 256, 0, stream>>>(eix, E, flag, bcnt, NB);
    bucket_scan_kernel<<<1, 512, 0, stream>>>(bcnt, boff, bcur, NB, N, E, row_ptr);
    partition_kernel<<<512, 256, 0, stream>>>(eix, E, flag, bcur, bdata);
    csr_build_kernel<<<NB, 256, 0, stream>>>(bdata, boff, N, row_ptr, csr_src);

    convert_x_kernel<<<2048, 256, 0, stream>>>(bufA, x, N * 32);
    pack_w_kernel<<<(7 * 2048 + 255) / 256, 256, 0, stream>>>(pk, W1, W2, l1W);

    const int gBlocks = 2048;
    const int mBlocks = (N + 127) / 128;

    __half* cur = bufA;
    __half* oth = bufB;
    for (int l = 0; l < 3; ++l) {
        gather_h_kernel<<<gBlocks, 256, 0, stream>>>(oth, cur, row_ptr, csr_src, eps, l, N);
        gemm_h_kernel<<<mBlocks, 256, 0, stream>>>(
            oth, pk + (size_t)l * 16384, b1 + l * 128, g1 + l * 128, bb1 + l * 128,
            m1 + l * 128, v1 + l * 128, oth, N);
        gemm_h_kernel<<<mBlocks, 256, 0, stream>>>(
            oth, pk + (size_t)(3 + l) * 16384, b2 + l * 128, g2 + l * 128, bb2 + l * 128,
            m2 + l * 128, v2 + l * 128, oth, N);
        __half* t = cur; cur = oth; oth = t;
    }
    // lin1 + ReLU (no BN)
    gemm_h_kernel<<<mBlocks, 256, 0, stream>>>(
        cur, pk + (size_t)6 * 16384, l1b, nullptr, nullptr, nullptr, nullptr, oth, N);
    // lin2 + log_softmax
    head_kernel<<<4096, 256, 0, stream>>>(oth, l2W, l2b, (float*)d_out, N);
}

// Round 8
// 440.982 us; speedup vs baseline: 2.2915x; 1.2247x over previous
//
#include <hip/hip_runtime.h>
#include <hip/hip_fp16.h>

// GIN: 3 layers of {CSR-gather aggregate fused with (1+eps)*x, fused MLP(2x GEMM128 via
// MFMA, BN folded, ReLU)}, then fused lin1+ReLU+lin2+log_softmax head.
// N=100000, E=1.6M. Round 8: 64-node buckets (partition atomic depth /4),
// GEMM1+GEMM2 fused through LDS, lin1+head fused.

#define BPAD 32   // ints per bucket counter slot (128B: one counter per cache line)

typedef _Float16 f16x8 __attribute__((ext_vector_type(8)));
typedef float f32x4 __attribute__((ext_vector_type(4)));

struct H4 { __half2 a, b; };   // 8B fp16 quad

// ---------------------------------------------------------------------------
// Detect whether edge_index is int64 (all high words zero) or int32.
__global__ void detect_idx_kernel(const unsigned int* __restrict__ w, long long nOdd,
                                  int* __restrict__ flag) {
    __shared__ int any;
    if (threadIdx.x == 0) any = 0;
    __syncthreads();
    for (long long i = threadIdx.x; i < nOdd; i += blockDim.x) {
        if (w[2 * i + 1] != 0u) { any = 1; break; }
    }
    __syncthreads();
    if (threadIdx.x == 0) *flag = (any == 0) ? 1 : 0;   // 1 => int64 layout
}

// ---------------------------------------------------------------------------
// Coarse histogram over 64-node buckets: bcnt[(dst>>6)*BPAD] += 1.
__global__ __launch_bounds__(256) void bucket_hist_kernel(
    const void* __restrict__ idx, long long E, const int* __restrict__ flag,
    int* __restrict__ bcnt, int NB) {
    __shared__ int h[2048];
    for (int i = threadIdx.x; i < 2048; i += 256) h[i] = 0;
    __syncthreads();
    long long i = (long long)blockIdx.x * blockDim.x + threadIdx.x;
    long long stride = (long long)gridDim.x * blockDim.x;
    if (*flag) {
        const long long* pd = (const long long*)idx + E;
        for (; i < E; i += stride) atomicAdd(&h[((int)pd[i]) >> 6], 1);
    } else {
        const int* pd = (const int*)idx + E;
        for (; i < E; i += stride) atomicAdd(&h[pd[i] >> 6], 1);
    }
    __syncthreads();
    for (int i = threadIdx.x; i < NB; i += 256) {
        int v = h[i];
        if (v) atomicAdd(&bcnt[i * BPAD], v);
    }
}

// ---------------------------------------------------------------------------
// Exclusive scan of NB (<=2048) bucket counts -> boff (compact), bcur (padded).
__global__ __launch_bounds__(1024) void bucket_scan_kernel(
    const int* __restrict__ bcnt, int* __restrict__ boff, int* __restrict__ bcur,
    int NB, int N, long long E, int* __restrict__ row_ptr) {
    int t = threadIdx.x;
    __shared__ int sh[1024];
    int i0 = 2 * t, i1 = 2 * t + 1;
    int c0 = (i0 < NB) ? bcnt[i0 * BPAD] : 0;
    int c1 = (i1 < NB) ? bcnt[i1 * BPAD] : 0;
    int s = c0 + c1;
    sh[t] = s;
    __syncthreads();
    for (int off = 1; off < 1024; off <<= 1) {
        int v = (t >= off) ? sh[t - off] : 0;
        __syncthreads();
        sh[t] += v;
        __syncthreads();
    }
    int excl = sh[t] - s;
    if (i0 < NB) { boff[i0] = excl;      bcur[i0 * BPAD] = excl; }
    if (i1 < NB) { boff[i1] = excl + c0; bcur[i1 * BPAD] = excl + c0; }
    if (t == 0) { boff[NB] = (int)E; row_ptr[N] = (int)E; }
}

// ---------------------------------------------------------------------------
// Partition edges into bucket regions: bdata[bcur[(dst>>6)*BPAD]++] = (src, dst).
__global__ __launch_bounds__(256) void partition_kernel(
    const void* __restrict__ idx, long long E, const int* __restrict__ flag,
    int* __restrict__ bcur, uint2* __restrict__ bdata) {
    long long i = (long long)blockIdx.x * blockDim.x + threadIdx.x;
    long long stride = (long long)gridDim.x * blockDim.x;
    if (*flag) {
        const long long* ps = (const long long*)idx;
        const long long* pd = ps + E;
        for (; i < E; i += stride) {
            int s = (int)ps[i], d = (int)pd[i];
            int pos = atomicAdd(&bcur[(d >> 6) * BPAD], 1);
            bdata[pos] = make_uint2((unsigned)s, (unsigned)d);
        }
    } else {
        const int* ps = (const int*)idx;
        const int* pd = ps + E;
        for (; i < E; i += stride) {
            int s = ps[i], d = pd[i];
            int pos = atomicAdd(&bcur[(d >> 6) * BPAD], 1);
            bdata[pos] = make_uint2((unsigned)s, (unsigned)d);
        }
    }
}

// ---------------------------------------------------------------------------
// Per-bucket CSR finalize (64 nodes/bucket): LDS hist, LDS scan, row_ptr write,
// then place src into csr_src (4KB window per bucket, L2-absorbed).
__global__ __launch_bounds__(256) void csr_build_kernel(
    const uint2* __restrict__ bdata, const int* __restrict__ boff, int N,
    int* __restrict__ row_ptr, int* __restrict__ csr_src) {
    int b = blockIdx.x, t = threadIdx.x;
    int lo = boff[b], hi = boff[b + 1];
    int nb = b << 6;
    __shared__ int cnt[64];
    __shared__ int shs[64];
    if (t < 64) cnt[t] = 0;
    __syncthreads();
    for (int i = lo + t; i < hi; i += 256)
        atomicAdd(&cnt[bdata[i].y & 63], 1);
    __syncthreads();
    int c = (t < 64) ? cnt[t] : 0;
    if (t < 64) shs[t] = c;
    __syncthreads();
    for (int off = 1; off < 64; off <<= 1) {
        int v = (t >= off && t < 64) ? shs[t - off] : 0;
        __syncthreads();
        if (t < 64) shs[t] += v;
        __syncthreads();
    }
    if (t < 64) {
        int excl = shs[t] - c;
        if (nb + t < N) row_ptr[nb + t] = lo + excl;
        cnt[t] = excl;                 // cursor: local absolute position
    }
    __syncthreads();
    for (int i = lo + t; i < hi; i += 256) {
        uint2 e = bdata[i];
        int p = atomicAdd(&cnt[e.y & 63], 1);
        csr_src[lo + p] = (int)e.x;
    }
}

// ---------------------------------------------------------------------------
// x fp32 [N,128] -> fp16.
__global__ void convert_x_kernel(__half* __restrict__ out, const float* __restrict__ in,
                                 int n4) {
    int i = blockIdx.x * blockDim.x + threadIdx.x;
    int stride = gridDim.x * blockDim.x;
    const float4* in4 = (const float4*)in;
    for (; i < n4; i += stride) {
        float4 v = in4[i];
        H4 h;
        h.a = __float22half2_rn(make_float2(v.x, v.y));
        h.b = __float22half2_rn(make_float2(v.z, v.w));
        *(H4*)(out + i * 4) = h;
    }
}

// ---------------------------------------------------------------------------
// Pack 7 fp32 [128][128] weight matrices (W1 l0..2, W2 l0..2, lin1) into fp16
// MFMA "A-operand" fragment order: pk[mat][((ks*8+ct)*64+lane)*8 + j] =
//   W[ks*32 + (lane>>4)*8 + j][ct*16 + (lane&15)]
__global__ void pack_w_kernel(__half* __restrict__ pk, const float* __restrict__ W1,
                              const float* __restrict__ W2, const float* __restrict__ lin1) {
    int t = blockIdx.x * blockDim.x + threadIdx.x;
    if (t >= 7 * 2048) return;
    int mat = t >> 11;
    int rem = t & 2047;
    int ks = rem >> 9;
    int ct = (rem >> 6) & 7;
    int lane = rem & 63;
    int g = lane >> 4, c = lane & 15;
    const float* src = (mat < 3) ? W1 + mat * 16384
                     : (mat < 6) ? W2 + (mat - 3) * 16384
                                 : lin1;
    __half* dst = pk + mat * 16384 + ((size_t)((ks * 8 + ct) * 64 + lane)) * 8;
#pragma unroll
    for (int j = 0; j < 8; ++j)
        dst[j] = (__half)src[(ks * 32 + g * 8 + j) * 128 + ct * 16 + c];
}

// ---------------------------------------------------------------------------
// out[n] = fp16( (1+eps)*x[n] + sum_j x[csr[j]] ), fp32 accumulate.
__global__ __launch_bounds__(256) void gather_h_kernel(
    __half* __restrict__ out, const __half* __restrict__ x,
    const int* __restrict__ row_ptr, const int* __restrict__ csr,
    const float* __restrict__ eps, int layer, int N) {
    int wave = threadIdx.x >> 6;
    int lane = threadIdx.x & 63;
    int wid = blockIdx.x * 4 + wave;
    int nw = gridDim.x * 4;
    float s = 1.0f + eps[layer];
    for (int n = wid; n < N; n += nw) {
        float2 acc = __half22float2(((const __half2*)(x + n * 128))[lane]);
        acc.x *= s; acc.y *= s;
        int beg = row_ptr[n], end = row_ptr[n + 1];
        int j = beg;
        for (; j + 3 < end; j += 4) {
            int s0 = csr[j], s1 = csr[j + 1], s2 = csr[j + 2], s3 = csr[j + 3];
            float2 v0 = __half22float2(((const __half2*)(x + s0 * 128))[lane]);
            float2 v1 = __half22float2(((const __half2*)(x + s1 * 128))[lane]);
            float2 v2 = __half22float2(((const __half2*)(x + s2 * 128))[lane]);
            float2 v3 = __half22float2(((const __half2*)(x + s3 * 128))[lane]);
            acc.x += (v0.x + v1.x) + (v2.x + v3.x);
            acc.y += (v0.y + v1.y) + (v2.y + v3.y);
        }
        for (; j < end; ++j) {
            float2 v = __half22float2(((const __half2*)(x + csr[j] * 128))[lane]);
            acc.x += v.x;
            acc.y += v.y;
        }
        ((__half2*)(out + n * 128))[lane] = __float22half2_rn(acc);
    }
}

// ---------------------------------------------------------------------------
// Fused MLP: out = relu(BN2(relu(BN1(in@W1+b1))@W2+b2)). 128 rows/block.
// GEMM1 epilogue writes fp16 h1 back into the SAME swizzled LDS tile (barrier-
// protected), GEMM2 consumes it. One global read + one global write per row.
// In-place safe (block reads only its own 128 rows).
__global__ __launch_bounds__(256) void gemm12_h_kernel(
    const __half* __restrict__ in,
    const __half* __restrict__ pk1, const float* __restrict__ b1,
    const float* __restrict__ g1, const float* __restrict__ bb1,
    const float* __restrict__ m1, const float* __restrict__ v1,
    const __half* __restrict__ pk2, const float* __restrict__ b2,
    const float* __restrict__ g2, const float* __restrict__ bb2,
    const float* __restrict__ m2, const float* __restrict__ v2,
    __half* __restrict__ out, int N) {
    __shared__ __half sA[128 * 128];
    __shared__ float sc1_s[128], sh1_s[128], sc2_s[128], sh2_s[128];

    const int tid = threadIdx.x;
    if (tid < 128) {
        int c = tid;
        float sc = g1[c] * rsqrtf(v1[c] + 1e-5f);
        sc1_s[c] = sc;
        sh1_s[c] = b1[c] * sc + bb1[c] - m1[c] * sc;
        sc = g2[c] * rsqrtf(v2[c] + 1e-5f);
        sc2_s[c] = sc;
        sh2_s[c] = b2[c] * sc + bb2[c] - m2[c] * sc;
    }

    const int base = blockIdx.x * 128;
#pragma unroll
    for (int q = 0; q < 8; ++q) {
        int i = tid + q * 256;
        int row = i >> 4, c = i & 15;
        int r = base + row;
        if (r >= N) r = N - 1;
        uint4 v = *(const uint4*)(in + r * 128 + c * 8);
        *(uint4*)&sA[row * 128 + ((c ^ (row & 15)) * 8)] = v;
    }
    __syncthreads();

    const int wave = tid >> 6;
    const int lane = tid & 63;
    const int g16 = lane >> 4;
    const int r15 = lane & 15;

    f32x4 acc[2][8];
#pragma unroll
    for (int rt = 0; rt < 2; ++rt)
#pragma unroll
        for (int ct = 0; ct < 8; ++ct) acc[rt][ct] = (f32x4)0.f;

    // ---- GEMM1 ----
#pragma unroll
    for (int ks = 0; ks < 4; ++ks) {
        f16x8 wf[8];
#pragma unroll
        for (int ct = 0; ct < 8; ++ct)
            wf[ct] = *(const f16x8*)(pk1 + ((ks * 8 + ct) * 64 + lane) * 8);
#pragma unroll
        for (int rt = 0; rt < 2; ++rt) {
            int row = wave * 32 + rt * 16 + r15;
            f16x8 bf = *(const f16x8*)&sA[row * 128 + (((ks * 4 + g16) ^ r15) * 8)];
#pragma unroll
            for (int ct = 0; ct < 8; ++ct)
                acc[rt][ct] = __builtin_amdgcn_mfma_f32_16x16x32_f16(wf[ct], bf,
                                                                     acc[rt][ct], 0, 0, 0);
        }
    }

    __syncthreads();   // all reads of sA done -> safe to overwrite
    // epilogue 1: BN1 + ReLU -> fp16 back into swizzled sA
#pragma unroll
    for (int rt = 0; rt < 2; ++rt) {
        int row = wave * 32 + rt * 16 + r15;
#pragma unroll
        for (int ct = 0; ct < 8; ++ct) {
            int col = ct * 16 + g16 * 4;
            float4 sc4 = *(float4*)&sc1_s[col];
            float4 sh4 = *(float4*)&sh1_s[col];
            f32x4 a = acc[rt][ct];
            float o0 = fmaxf(fmaf(a[0], sc4.x, sh4.x), 0.f);
            float o1 = fmaxf(fmaf(a[1], sc4.y, sh4.y), 0.f);
            float o2 = fmaxf(fmaf(a[2], sc4.z, sh4.z), 0.f);
            float o3 = fmaxf(fmaf(a[3], sc4.w, sh4.w), 0.f);
            H4 h;
            h.a = __float22half2_rn(make_float2(o0, o1));
            h.b = __float22half2_rn(make_float2(o2, o3));
            int c = col >> 3;
            *(H4*)&sA[row * 128 + ((c ^ (row & 15)) * 8) + (col & 7)] = h;
        }
    }
    __syncthreads();

    // ---- GEMM2 ----
#pragma unroll
    for (int rt = 0; rt < 2; ++rt)
#pragma unroll
        for (int ct = 0; ct < 8; ++ct) acc[rt][ct] = (f32x4)0.f;
#pragma unroll
    for (int ks = 0; ks < 4; ++ks) {
        f16x8 wf[8];
#pragma unroll
        for (int ct = 0; ct < 8; ++ct)
            wf[ct] = *(const f16x8*)(pk2 + ((ks * 8 + ct) * 64 + lane) * 8);
#pragma unroll
        for (int rt = 0; rt < 2; ++rt) {
            int row = wave * 32 + rt * 16 + r15;
            f16x8 bf = *(const f16x8*)&sA[row * 128 + (((ks * 4 + g16) ^ r15) * 8)];
#pragma unroll
            for (int ct = 0; ct < 8; ++ct)
                acc[rt][ct] = __builtin_amdgcn_mfma_f32_16x16x32_f16(wf[ct], bf,
                                                                     acc[rt][ct], 0, 0, 0);
        }
    }

    // epilogue 2: BN2 + ReLU -> global fp16
#pragma unroll
    for (int rt = 0; rt < 2; ++rt) {
        int r = base + wave * 32 + rt * 16 + r15;
        if (r < N) {
            __half* orow = out + r * 128;
#pragma unroll
            for (int ct = 0; ct < 8; ++ct) {
                int col = ct * 16 + g16 * 4;
                float4 sc4 = *(float4*)&sc2_s[col];
                float4 sh4 = *(float4*)&sh2_s[col];
                f32x4 a = acc[rt][ct];
                float o0 = fmaxf(fmaf(a[0], sc4.x, sh4.x), 0.f);
                float o1 = fmaxf(fmaf(a[1], sc4.y, sh4.y), 0.f);
                float o2 = fmaxf(fmaf(a[2], sc4.z, sh4.z), 0.f);
                float o3 = fmaxf(fmaf(a[3], sc4.w, sh4.w), 0.f);
                H4 h;
                h.a = __float22half2_rn(make_float2(o0, o1));
                h.b = __float22half2_rn(make_float2(o2, o3));
                *(H4*)(orow + col) = h;
            }
        }
    }
}

// ---------------------------------------------------------------------------
// Fused head: h = relu(in@lin1W+lin1b) (MFMA, fp32 acc); logits = h@lin2W+lin2b;
// out = log_softmax. Row's 128 h-values live across 4 lanes (g16 group) ->
// per-lane partial logits, shfl_xor(16|32) reduce, g16==0 lane finishes.
__global__ __launch_bounds__(256) void lin1_head_kernel(
    const __half* __restrict__ in, const __half* __restrict__ pk1,
    const float* __restrict__ l1b, const float* __restrict__ l2W,
    const float* __restrict__ l2b, float* __restrict__ out, int N) {
    __shared__ __half sA[128 * 128];
    __shared__ float Wl[1280];
    __shared__ float bl[10];
    __shared__ float b1_s[128];

    const int tid = threadIdx.x;
    for (int i = tid; i < 1280; i += 256) Wl[i] = l2W[i];
    if (tid < 10) bl[tid] = l2b[tid];
    if (tid < 128) b1_s[tid] = l1b[tid];

    const int base = blockIdx.x * 128;
#pragma unroll
    for (int q = 0; q < 8; ++q) {
        int i = tid + q * 256;
        int row = i >> 4, c = i & 15;
        int r = base + row;
        if (r >= N) r = N - 1;
        uint4 v = *(const uint4*)(in + r * 128 + c * 8);
        *(uint4*)&sA[row * 128 + ((c ^ (row & 15)) * 8)] = v;
    }
    __syncthreads();

    const int wave = tid >> 6;
    const int lane = tid & 63;
    const int g16 = lane >> 4;
    const int r15 = lane & 15;

    f32x4 acc[2][8];
#pragma unroll
    for (int rt = 0; rt < 2; ++rt)
#pragma unroll
        for (int ct = 0; ct < 8; ++ct) acc[rt][ct] = (f32x4)0.f;

#pragma unroll
    for (int ks = 0; ks < 4; ++ks) {
        f16x8 wf[8];
#pragma unroll
        for (int ct = 0; ct < 8; ++ct)
            wf[ct] = *(const f16x8*)(pk1 + ((ks * 8 + ct) * 64 + lane) * 8);
#pragma unroll
        for (int rt = 0; rt < 2; ++rt) {
            int row = wave * 32 + rt * 16 + r15;
            f16x8 bf = *(const f16x8*)&sA[row * 128 + (((ks * 4 + g16) ^ r15) * 8)];
#pragma unroll
            for (int ct = 0; ct < 8; ++ct)
                acc[rt][ct] = __builtin_amdgcn_mfma_f32_16x16x32_f16(wf[ct], bf,
                                                                     acc[rt][ct], 0, 0, 0);
        }
    }

#pragma unroll
    for (int rt = 0; rt < 2; ++rt) {
        float p[10];
#pragma unroll
        for (int c = 0; c < 10; ++c) p[c] = 0.f;
#pragma unroll
        for (int ct = 0; ct < 8; ++ct) {
            int col0 = ct * 16 + g16 * 4;
#pragma unroll
            for (int j = 0; j < 4; ++j) {
                int col = col0 + j;
                float h = fmaxf(acc[rt][ct][j] + b1_s[col], 0.f);
#pragma unroll
                for (int c = 0; c < 10; ++c) p[c] = fmaf(h, Wl[col * 10 + c], p[c]);
            }
        }
#pragma unroll
        for (int c = 0; c < 10; ++c) {
            p[c] += __shfl_xor(p[c], 16);
            p[c] += __shfl_xor(p[c], 32);
        }
        int r = base + wave * 32 + rt * 16 + r15;
        if (g16 == 0 && r < N) {
            float mx = -1e30f;
#pragma unroll
            for (int c = 0; c < 10; ++c) {
                p[c] += bl[c];
                mx = fmaxf(mx, p[c]);
            }
            float sum = 0.f;
#pragma unroll
            for (int c = 0; c < 10; ++c) sum += expf(p[c] - mx);
            float lse = mx + logf(sum);
            float* orow = out + (long long)r * 10;
#pragma unroll
            for (int c = 0; c < 10; ++c) orow[c] = p[c] - lse;
        }
    }
}

// ---------------------------------------------------------------------------
extern "C" void kernel_launch(void* const* d_in, const int* in_sizes, int n_in,
                              void* d_out, int out_size, void* d_ws, size_t ws_size,
                              hipStream_t stream) {
    const float* x   = (const float*)d_in[0];
    const void*  eix = d_in[1];
    const float* eps = (const float*)d_in[2];
    const float* W1  = (const float*)d_in[3];
    const float* b1  = (const float*)d_in[4];
    const float* g1  = (const float*)d_in[5];
    const float* bb1 = (const float*)d_in[6];
    const float* m1  = (const float*)d_in[7];
    const float* v1  = (const float*)d_in[8];
    const float* W2  = (const float*)d_in[9];
    const float* b2  = (const float*)d_in[10];
    const float* g2  = (const float*)d_in[11];
    const float* bb2 = (const float*)d_in[12];
    const float* m2  = (const float*)d_in[13];
    const float* v2  = (const float*)d_in[14];
    const float* l1W = (const float*)d_in[15];
    const float* l1b = (const float*)d_in[16];
    const float* l2W = (const float*)d_in[17];
    const float* l2b = (const float*)d_in[18];

    const int N = in_sizes[0] / 128;
    const long long E = in_sizes[1] / 2;
    const int NB = (N + 63) >> 6;             // 64-node buckets (<=2048)

    // workspace layout (16B-aligned blocks first)
    __half* bufA  = (__half*)d_ws;                     // N*128 fp16
    __half* bufB  = bufA + (size_t)N * 128;            // N*128 fp16
    __half* pk    = bufB + (size_t)N * 128;            // 7*16384 fp16
    uint2*  bdata = (uint2*)(pk + 7 * 16384);          // E pairs (8B)
    int* csr_src  = (int*)(bdata + E);                 // E
    int* row_ptr  = csr_src + E;                       // N+1
    int* bcnt     = row_ptr + N + 1;                   // 2048*BPAD (padded)
    int* bcur     = bcnt + 2048 * BPAD;                // 2048*BPAD (padded)
    int* boff     = bcur + 2048 * BPAD;                // 2049
    int* flag     = boff + 2049;                       // 1

    detect_idx_kernel<<<1, 256, 0, stream>>>((const unsigned int*)eix,
                                             (E < 2048 ? E : 2048), flag);
    hipMemsetAsync(bcnt, 0, (size_t)2048 * BPAD * sizeof(int), stream);

    bucket_hist_kernel<<<256, 256, 0, stream>>>(eix, E, flag, bcnt, NB);
    bucket_scan_kernel<<<1, 1024, 0, stream>>>(bcnt, boff, bcur, NB, N, E, row_ptr);
    partition_kernel<<<512, 256, 0, stream>>>(eix, E, flag, bcur, bdata);
    csr_build_kernel<<<NB, 256, 0, stream>>>(bdata, boff, N, row_ptr, csr_src);

    convert_x_kernel<<<2048, 256, 0, stream>>>(bufA, x, N * 32);
    pack_w_kernel<<<(7 * 2048 + 255) / 256, 256, 0, stream>>>(pk, W1, W2, l1W);

    const int gBlocks = 2048;
    const int mBlocks = (N + 127) / 128;

    __half* cur = bufA;
    __half* oth = bufB;
    for (int l = 0; l < 3; ++l) {
        gather_h_kernel<<<gBlocks, 256, 0, stream>>>(oth, cur, row_ptr, csr_src, eps, l, N);
        gemm12_h_kernel<<<mBlocks, 256, 0, stream>>>(
            oth,
            pk + (size_t)l * 16384, b1 + l * 128, g1 + l * 128, bb1 + l * 128,
            m1 + l * 128, v1 + l * 128,
            pk + (size_t)(3 + l) * 16384, b2 + l * 128, g2 + l * 128, bb2 + l * 128,
            m2 + l * 128, v2 + l * 128,
            oth, N);
        __half* t = cur; cur = oth; oth = t;
    }
    // fused lin1 + ReLU + lin2 + log_softmax
    lin1_head_kernel<<<mBlocks, 256, 0, stream>>>(
        cur, pk + (size_t)6 * 16384, l1b, l2W, l2b, (float*)d_out, N);
}

// Round 9
// 346.242 us; speedup vs baseline: 2.9185x; 1.2736x over previous
//
#include <hip/hip_runtime.h>
#include <hip/hip_fp16.h>

// GIN: 3 layers of {CSR-gather aggregate fused with (1+eps)*x, fused MLP(2x GEMM128 via
// MFMA, BN folded, ReLU)}, then fused lin1+ReLU+lin2+log_softmax head.
// N=100000, E=1.6M. Round 9: atomic-free two-pass radix partition (LDS hist +
// scanned (bucket,block) offset matrix + LDS-cursor scatter). 256-node buckets.

#define PB 256    // partition blocks
#define MAXNB 512 // max buckets (N <= 131072)

typedef _Float16 f16x8 __attribute__((ext_vector_type(8)));
typedef float f32x4 __attribute__((ext_vector_type(4)));

struct H4 { __half2 a, b; };   // 8B fp16 quad

// ---------------------------------------------------------------------------
// Detect whether edge_index is int64 (all high words zero) or int32.
__global__ void detect_idx_kernel(const unsigned int* __restrict__ w, long long nOdd,
                                  int* __restrict__ flag) {
    __shared__ int any;
    if (threadIdx.x == 0) any = 0;
    __syncthreads();
    for (long long i = threadIdx.x; i < nOdd; i += blockDim.x) {
        if (w[2 * i + 1] != 0u) { any = 1; break; }
    }
    __syncthreads();
    if (threadIdx.x == 0) *flag = (any == 0) ? 1 : 0;   // 1 => int64 layout
}

// ---------------------------------------------------------------------------
// Pass 1: per-block LDS histogram over 256-node buckets -> cnt_mat[bucket][block].
__global__ __launch_bounds__(256) void p1_hist_kernel(
    const void* __restrict__ idx, long long E, const int* __restrict__ flag,
    int* __restrict__ cnt_mat, int NB) {
    __shared__ int h[MAXNB];
    for (int i = threadIdx.x; i < MAXNB; i += 256) h[i] = 0;
    __syncthreads();
    const long long C = (E + PB - 1) / PB;
    const long long lo = (long long)blockIdx.x * C;
    long long hi = lo + C; if (hi > E) hi = E;
    if (*flag) {
        const long long* pd = (const long long*)idx + E;
        for (long long i = lo + threadIdx.x; i < hi; i += 256)
            atomicAdd(&h[((int)pd[i]) >> 8], 1);
    } else {
        const int* pd = (const int*)idx + E;
        for (long long i = lo + threadIdx.x; i < hi; i += 256)
            atomicAdd(&h[pd[i] >> 8], 1);
    }
    __syncthreads();
    for (int i = threadIdx.x; i < NB; i += 256)
        cnt_mat[i * PB + blockIdx.x] = h[i];
}

// ---------------------------------------------------------------------------
// Per-bucket exclusive scan over the PB block-counts (in place) + bucket total.
__global__ __launch_bounds__(256) void scan_bucket_kernel(
    int* __restrict__ cnt_mat, int* __restrict__ btotal) {
    int k = blockIdx.x, t = threadIdx.x;
    __shared__ int sh[PB];
    int c = cnt_mat[k * PB + t];
    sh[t] = c;
    __syncthreads();
    for (int off = 1; off < PB; off <<= 1) {
        int v = (t >= off) ? sh[t - off] : 0;
        __syncthreads();
        sh[t] += v;
        __syncthreads();
    }
    cnt_mat[k * PB + t] = sh[t] - c;        // exclusive within bucket
    if (t == PB - 1) btotal[k] = sh[t];
}

// ---------------------------------------------------------------------------
// Exclusive scan of bucket totals -> bbase, boff; row_ptr[N] = E.
__global__ __launch_bounds__(512) void scan_btotal_kernel(
    const int* __restrict__ btotal, int* __restrict__ bbase, int* __restrict__ boff,
    int NB, int N, long long E, int* __restrict__ row_ptr) {
    int t = threadIdx.x;
    __shared__ int sh[512];
    int c = (t < NB) ? btotal[t] : 0;
    sh[t] = c;
    __syncthreads();
    for (int off = 1; off < 512; off <<= 1) {
        int v = (t >= off) ? sh[t - off] : 0;
        __syncthreads();
        sh[t] += v;
        __syncthreads();
    }
    int excl = sh[t] - c;
    if (t < NB) { bbase[t] = excl; boff[t] = excl; }
    if (t == 0) { boff[NB] = (int)E; row_ptr[N] = (int)E; }
}

// ---------------------------------------------------------------------------
// Pass 2: re-read chunk, LDS cursors seeded with global dense offsets, scatter
// (src,dst) into bucket-grouped bdata. Zero global atomics.
__global__ __launch_bounds__(256) void p2_scatter_kernel(
    const void* __restrict__ idx, long long E, const int* __restrict__ flag,
    const int* __restrict__ cnt_mat, const int* __restrict__ bbase,
    uint2* __restrict__ bdata, int NB) {
    __shared__ int cur[MAXNB];
    int b = blockIdx.x;
    for (int i = threadIdx.x; i < NB; i += 256)
        cur[i] = cnt_mat[i * PB + b] + bbase[i];
    __syncthreads();
    const long long C = (E + PB - 1) / PB;
    const long long lo = (long long)b * C;
    long long hi = lo + C; if (hi > E) hi = E;
    if (*flag) {
        const long long* ps = (const long long*)idx;
        const long long* pd = ps + E;
        for (long long i = lo + threadIdx.x; i < hi; i += 256) {
            int s = (int)ps[i], d = (int)pd[i];
            int r = atomicAdd(&cur[d >> 8], 1);
            bdata[r] = make_uint2((unsigned)s, (unsigned)d);
        }
    } else {
        const int* ps = (const int*)idx;
        const int* pd = ps + E;
        for (long long i = lo + threadIdx.x; i < hi; i += 256) {
            int s = ps[i], d = pd[i];
            int r = atomicAdd(&cur[d >> 8], 1);
            bdata[r] = make_uint2((unsigned)s, (unsigned)d);
        }
    }
}

// ---------------------------------------------------------------------------
// Per-bucket CSR finalize (256 nodes/bucket): LDS hist, LDS scan, row_ptr write,
// then place src into csr_src (16KB window per bucket, L2-absorbed).
__global__ __launch_bounds__(256) void csr_build_kernel(
    const uint2* __restrict__ bdata, const int* __restrict__ boff, int N,
    int* __restrict__ row_ptr, int* __restrict__ csr_src) {
    int b = blockIdx.x, t = threadIdx.x;
    int lo = boff[b], hi = boff[b + 1];
    int nb = b << 8;
    __shared__ int cnt[256];
    __shared__ int sh[256];
    cnt[t] = 0;
    __syncthreads();
    for (int i = lo + t; i < hi; i += 256)
        atomicAdd(&cnt[bdata[i].y & 255], 1);
    __syncthreads();
    int c = cnt[t];
    sh[t] = c;
    __syncthreads();
    for (int off = 1; off < 256; off <<= 1) {
        int v = (t >= off) ? sh[t - off] : 0;
        __syncthreads();
        sh[t] += v;
        __syncthreads();
    }
    int excl = sh[t] - c;
    if (nb + t < N) row_ptr[nb + t] = lo + excl;
    cnt[t] = excl;                 // cursor: local absolute position
    __syncthreads();
    for (int i = lo + t; i < hi; i += 256) {
        uint2 e = bdata[i];
        int p = atomicAdd(&cnt[e.y & 255], 1);
        csr_src[lo + p] = (int)e.x;
    }
}

// ---------------------------------------------------------------------------
// x fp32 [N,128] -> fp16.
__global__ void convert_x_kernel(__half* __restrict__ out, const float* __restrict__ in,
                                 int n4) {
    int i = blockIdx.x * blockDim.x + threadIdx.x;
    int stride = gridDim.x * blockDim.x;
    const float4* in4 = (const float4*)in;
    for (; i < n4; i += stride) {
        float4 v = in4[i];
        H4 h;
        h.a = __float22half2_rn(make_float2(v.x, v.y));
        h.b = __float22half2_rn(make_float2(v.z, v.w));
        *(H4*)(out + i * 4) = h;
    }
}

// ---------------------------------------------------------------------------
// Pack 7 fp32 [128][128] weight matrices (W1 l0..2, W2 l0..2, lin1) into fp16
// MFMA "A-operand" fragment order: pk[mat][((ks*8+ct)*64+lane)*8 + j] =
//   W[ks*32 + (lane>>4)*8 + j][ct*16 + (lane&15)]
__global__ void pack_w_kernel(__half* __restrict__ pk, const float* __restrict__ W1,
                              const float* __restrict__ W2, const float* __restrict__ lin1) {
    int t = blockIdx.x * blockDim.x + threadIdx.x;
    if (t >= 7 * 2048) return;
    int mat = t >> 11;
    int rem = t & 2047;
    int ks = rem >> 9;
    int ct = (rem >> 6) & 7;
    int lane = rem & 63;
    int g = lane >> 4, c = lane & 15;
    const float* src = (mat < 3) ? W1 + mat * 16384
                     : (mat < 6) ? W2 + (mat - 3) * 16384
                                 : lin1;
    __half* dst = pk + mat * 16384 + ((size_t)((ks * 8 + ct) * 64 + lane)) * 8;
#pragma unroll
    for (int j = 0; j < 8; ++j)
        dst[j] = (__half)src[(ks * 32 + g * 8 + j) * 128 + ct * 16 + c];
}

// ---------------------------------------------------------------------------
// out[n] = fp16( (1+eps)*x[n] + sum_j x[csr[j]] ), fp32 accumulate.
// One wave per node, half2 per lane, unroll x8 for read MLP.
__global__ __launch_bounds__(256) void gather_h_kernel(
    __half* __restrict__ out, const __half* __restrict__ x,
    const int* __restrict__ row_ptr, const int* __restrict__ csr,
    const float* __restrict__ eps, int layer, int N) {
    int wave = threadIdx.x >> 6;
    int lane = threadIdx.x & 63;
    int wid = blockIdx.x * 4 + wave;
    int nw = gridDim.x * 4;
    float s = 1.0f + eps[layer];
    for (int n = wid; n < N; n += nw) {
        float2 acc = __half22float2(((const __half2*)(x + n * 128))[lane]);
        acc.x *= s; acc.y *= s;
        int beg = row_ptr[n], end = row_ptr[n + 1];
        int j = beg;
        for (; j + 7 < end; j += 8) {
            float2 v0 = __half22float2(((const __half2*)(x + csr[j + 0] * 128))[lane]);
            float2 v1 = __half22float2(((const __half2*)(x + csr[j + 1] * 128))[lane]);
            float2 v2 = __half22float2(((const __half2*)(x + csr[j + 2] * 128))[lane]);
            float2 v3 = __half22float2(((const __half2*)(x + csr[j + 3] * 128))[lane]);
            float2 v4 = __half22float2(((const __half2*)(x + csr[j + 4] * 128))[lane]);
            float2 v5 = __half22float2(((const __half2*)(x + csr[j + 5] * 128))[lane]);
            float2 v6 = __half22float2(((const __half2*)(x + csr[j + 6] * 128))[lane]);
            float2 v7 = __half22float2(((const __half2*)(x + csr[j + 7] * 128))[lane]);
            acc.x += ((v0.x + v1.x) + (v2.x + v3.x)) + ((v4.x + v5.x) + (v6.x + v7.x));
            acc.y += ((v0.y + v1.y) + (v2.y + v3.y)) + ((v4.y + v5.y) + (v6.y + v7.y));
        }
        for (; j + 1 < end; j += 2) {
            float2 v0 = __half22float2(((const __half2*)(x + csr[j] * 128))[lane]);
            float2 v1 = __half22float2(((const __half2*)(x + csr[j + 1] * 128))[lane]);
            acc.x += v0.x + v1.x;
            acc.y += v0.y + v1.y;
        }
        if (j < end) {
            float2 v = __half22float2(((const __half2*)(x + csr[j] * 128))[lane]);
            acc.x += v.x;
            acc.y += v.y;
        }
        ((__half2*)(out + n * 128))[lane] = __float22half2_rn(acc);
    }
}

// ---------------------------------------------------------------------------
// Fused MLP: out = relu(BN2(relu(BN1(in@W1+b1))@W2+b2)). 128 rows/block.
// GEMM1 epilogue writes fp16 h1 back into the SAME swizzled LDS tile (barrier-
// protected), GEMM2 consumes it. In-place safe.
__global__ __launch_bounds__(256) void gemm12_h_kernel(
    const __half* __restrict__ in,
    const __half* __restrict__ pk1, const float* __restrict__ b1,
    const float* __restrict__ g1, const float* __restrict__ bb1,
    const float* __restrict__ m1, const float* __restrict__ v1,
    const __half* __restrict__ pk2, const float* __restrict__ b2,
    const float* __restrict__ g2, const float* __restrict__ bb2,
    const float* __restrict__ m2, const float* __restrict__ v2,
    __half* __restrict__ out, int N) {
    __shared__ __half sA[128 * 128];
    __shared__ float sc1_s[128], sh1_s[128], sc2_s[128], sh2_s[128];

    const int tid = threadIdx.x;
    if (tid < 128) {
        int c = tid;
        float sc = g1[c] * rsqrtf(v1[c] + 1e-5f);
        sc1_s[c] = sc;
        sh1_s[c] = b1[c] * sc + bb1[c] - m1[c] * sc;
        sc = g2[c] * rsqrtf(v2[c] + 1e-5f);
        sc2_s[c] = sc;
        sh2_s[c] = b2[c] * sc + bb2[c] - m2[c] * sc;
    }

    const int base = blockIdx.x * 128;
#pragma unroll
    for (int q = 0; q < 8; ++q) {
        int i = tid + q * 256;
        int row = i >> 4, c = i & 15;
        int r = base + row;
        if (r >= N) r = N - 1;
        uint4 v = *(const uint4*)(in + r * 128 + c * 8);
        *(uint4*)&sA[row * 128 + ((c ^ (row & 15)) * 8)] = v;
    }
    __syncthreads();

    const int wave = tid >> 6;
    const int lane = tid & 63;
    const int g16 = lane >> 4;
    const int r15 = lane & 15;

    f32x4 acc[2][8];
#pragma unroll
    for (int rt = 0; rt < 2; ++rt)
#pragma unroll
        for (int ct = 0; ct < 8; ++ct) acc[rt][ct] = (f32x4)0.f;

    // ---- GEMM1 ----
#pragma unroll
    for (int ks = 0; ks < 4; ++ks) {
        f16x8 wf[8];
#pragma unroll
        for (int ct = 0; ct < 8; ++ct)
            wf[ct] = *(const f16x8*)(pk1 + ((ks * 8 + ct) * 64 + lane) * 8);
#pragma unroll
        for (int rt = 0; rt < 2; ++rt) {
            int row = wave * 32 + rt * 16 + r15;
            f16x8 bf = *(const f16x8*)&sA[row * 128 + (((ks * 4 + g16) ^ r15) * 8)];
#pragma unroll
            for (int ct = 0; ct < 8; ++ct)
                acc[rt][ct] = __builtin_amdgcn_mfma_f32_16x16x32_f16(wf[ct], bf,
                                                                     acc[rt][ct], 0, 0, 0);
        }
    }

    __syncthreads();   // all reads of sA done -> safe to overwrite
    // epilogue 1: BN1 + ReLU -> fp16 back into swizzled sA
#pragma unroll
    for (int rt = 0; rt < 2; ++rt) {
        int row = wave * 32 + rt * 16 + r15;
#pragma unroll
        for (int ct = 0; ct < 8; ++ct) {
            int col = ct * 16 + g16 * 4;
            float4 sc4 = *(float4*)&sc1_s[col];
            float4 sh4 = *(float4*)&sh1_s[col];
            f32x4 a = acc[rt][ct];
            float o0 = fmaxf(fmaf(a[0], sc4.x, sh4.x), 0.f);
            float o1 = fmaxf(fmaf(a[1], sc4.y, sh4.y), 0.f);
            float o2 = fmaxf(fmaf(a[2], sc4.z, sh4.z), 0.f);
            float o3 = fmaxf(fmaf(a[3], sc4.w, sh4.w), 0.f);
            H4 h;
            h.a = __float22half2_rn(make_float2(o0, o1));
            h.b = __float22half2_rn(make_float2(o2, o3));
            int c = col >> 3;
            *(H4*)&sA[row * 128 + ((c ^ (row & 15)) * 8) + (col & 7)] = h;
        }
    }
    __syncthreads();

    // ---- GEMM2 ----
#pragma unroll
    for (int rt = 0; rt < 2; ++rt)
#pragma unroll
        for (int ct = 0; ct < 8; ++ct) acc[rt][ct] = (f32x4)0.f;
#pragma unroll
    for (int ks = 0; ks < 4; ++ks) {
        f16x8 wf[8];
#pragma unroll
        for (int ct = 0; ct < 8; ++ct)
            wf[ct] = *(const f16x8*)(pk2 + ((ks * 8 + ct) * 64 + lane) * 8);
#pragma unroll
        for (int rt = 0; rt < 2; ++rt) {
            int row = wave * 32 + rt * 16 + r15;
            f16x8 bf = *(const f16x8*)&sA[row * 128 + (((ks * 4 + g16) ^ r15) * 8)];
#pragma unroll
            for (int ct = 0; ct < 8; ++ct)
                acc[rt][ct] = __builtin_amdgcn_mfma_f32_16x16x32_f16(wf[ct], bf,
                                                                     acc[rt][ct], 0, 0, 0);
        }
    }

    // epilogue 2: BN2 + ReLU -> global fp16
#pragma unroll
    for (int rt = 0; rt < 2; ++rt) {
        int r = base + wave * 32 + rt * 16 + r15;
        if (r < N) {
            __half* orow = out + r * 128;
#pragma unroll
            for (int ct = 0; ct < 8; ++ct) {
                int col = ct * 16 + g16 * 4;
                float4 sc4 = *(float4*)&sc2_s[col];
                float4 sh4 = *(float4*)&sh2_s[col];
                f32x4 a = acc[rt][ct];
                float o0 = fmaxf(fmaf(a[0], sc4.x, sh4.x), 0.f);
                float o1 = fmaxf(fmaf(a[1], sc4.y, sh4.y), 0.f);
                float o2 = fmaxf(fmaf(a[2], sc4.z, sh4.z), 0.f);
                float o3 = fmaxf(fmaf(a[3], sc4.w, sh4.w), 0.f);
                H4 h;
                h.a = __float22half2_rn(make_float2(o0, o1));
                h.b = __float22half2_rn(make_float2(o2, o3));
                *(H4*)(orow + col) = h;
            }
        }
    }
}

// ---------------------------------------------------------------------------
// Fused head: h = relu(in@lin1W+lin1b); logits = h@lin2W+lin2b; log_softmax.
__global__ __launch_bounds__(256) void lin1_head_kernel(
    const __half* __restrict__ in, const __half* __restrict__ pk1,
    const float* __restrict__ l1b, const float* __restrict__ l2W,
    const float* __restrict__ l2b, float* __restrict__ out, int N) {
    __shared__ __half sA[128 * 128];
    __shared__ float Wl[1280];
    __shared__ float bl[10];
    __shared__ float b1_s[128];

    const int tid = threadIdx.x;
    for (int i = tid; i < 1280; i += 256) Wl[i] = l2W[i];
    if (tid < 10) bl[tid] = l2b[tid];
    if (tid < 128) b1_s[tid] = l1b[tid];

    const int base = blockIdx.x * 128;
#pragma unroll
    for (int q = 0; q < 8; ++q) {
        int i = tid + q * 256;
        int row = i >> 4, c = i & 15;
        int r = base + row;
        if (r >= N) r = N - 1;
        uint4 v = *(const uint4*)(in + r * 128 + c * 8);
        *(uint4*)&sA[row * 128 + ((c ^ (row & 15)) * 8)] = v;
    }
    __syncthreads();

    const int wave = tid >> 6;
    const int lane = tid & 63;
    const int g16 = lane >> 4;
    const int r15 = lane & 15;

    f32x4 acc[2][8];
#pragma unroll
    for (int rt = 0; rt < 2; ++rt)
#pragma unroll
        for (int ct = 0; ct < 8; ++ct) acc[rt][ct] = (f32x4)0.f;

#pragma unroll
    for (int ks = 0; ks < 4; ++ks) {
        f16x8 wf[8];
#pragma unroll
        for (int ct = 0; ct < 8; ++ct)
            wf[ct] = *(const f16x8*)(pk1 + ((ks * 8 + ct) * 64 + lane) * 8);
#pragma unroll
        for (int rt = 0; rt < 2; ++rt) {
            int row = wave * 32 + rt * 16 + r15;
            f16x8 bf = *(const f16x8*)&sA[row * 128 + (((ks * 4 + g16) ^ r15) * 8)];
#pragma unroll
            for (int ct = 0; ct < 8; ++ct)
                acc[rt][ct] = __builtin_amdgcn_mfma_f32_16x16x32_f16(wf[ct], bf,
                                                                     acc[rt][ct], 0, 0, 0);
        }
    }

#pragma unroll
    for (int rt = 0; rt < 2; ++rt) {
        float p[10];
#pragma unroll
        for (int c = 0; c < 10; ++c) p[c] = 0.f;
#pragma unroll
        for (int ct = 0; ct < 8; ++ct) {
            int col0 = ct * 16 + g16 * 4;
#pragma unroll
            for (int j = 0; j < 4; ++j) {
                int col = col0 + j;
                float h = fmaxf(acc[rt][ct][j] + b1_s[col], 0.f);
#pragma unroll
                for (int c = 0; c < 10; ++c) p[c] = fmaf(h, Wl[col * 10 + c], p[c]);
            }
        }
#pragma unroll
        for (int c = 0; c < 10; ++c) {
            p[c] += __shfl_xor(p[c], 16);
            p[c] += __shfl_xor(p[c], 32);
        }
        int r = base + wave * 32 + rt * 16 + r15;
        if (g16 == 0 && r < N) {
            float mx = -1e30f;
#pragma unroll
            for (int c = 0; c < 10; ++c) {
                p[c] += bl[c];
                mx = fmaxf(mx, p[c]);
            }
            float sum = 0.f;
#pragma unroll
            for (int c = 0; c < 10; ++c) sum += expf(p[c] - mx);
            float lse = mx + logf(sum);
            float* orow = out + (long long)r * 10;
#pragma unroll
            for (int c = 0; c < 10; ++c) orow[c] = p[c] - lse;
        }
    }
}

// ---------------------------------------------------------------------------
extern "C" void kernel_launch(void* const* d_in, const int* in_sizes, int n_in,
                              void* d_out, int out_size, void* d_ws, size_t ws_size,
                              hipStream_t stream) {
    const float* x   = (const float*)d_in[0];
    const void*  eix = d_in[1];
    const float* eps = (const float*)d_in[2];
    const float* W1  = (const float*)d_in[3];
    const float* b1  = (const float*)d_in[4];
    const float* g1  = (const float*)d_in[5];
    const float* bb1 = (const float*)d_in[6];
    const float* m1  = (const float*)d_in[7];
    const float* v1  = (const float*)d_in[8];
    const float* W2  = (const float*)d_in[9];
    const float* b2  = (const float*)d_in[10];
    const float* g2  = (const float*)d_in[11];
    const float* bb2 = (const float*)d_in[12];
    const float* m2  = (const float*)d_in[13];
    const float* v2  = (const float*)d_in[14];
    const float* l1W = (const float*)d_in[15];
    const float* l1b = (const float*)d_in[16];
    const float* l2W = (const float*)d_in[17];
    const float* l2b = (const float*)d_in[18];

    const int N = in_sizes[0] / 128;
    const long long E = in_sizes[1] / 2;
    const int NB = (N + 255) >> 8;            // 256-node buckets (<=512)

    // workspace layout (16B-aligned blocks first)
    __half* bufA  = (__half*)d_ws;                     // N*128 fp16
    __half* bufB  = bufA + (size_t)N * 128;            // N*128 fp16
    __half* pk    = bufB + (size_t)N * 128;            // 7*16384 fp16
    uint2*  bdata = (uint2*)(pk + 7 * 16384);          // E pairs (8B)
    int* csr_src  = (int*)(bdata + E);                 // E
    int* row_ptr  = csr_src + E;                       // N+1
    int* cnt_mat  = row_ptr + N + 1;                   // MAXNB*PB
    int* btotal   = cnt_mat + MAXNB * PB;              // MAXNB
    int* bbase    = btotal + MAXNB;                    // MAXNB
    int* boff     = bbase + MAXNB;                     // MAXNB+1
    int* flag     = boff + MAXNB + 1;                  // 1

    detect_idx_kernel<<<1, 256, 0, stream>>>((const unsigned int*)eix,
                                             (E < 2048 ? E : 2048), flag);

    p1_hist_kernel<<<PB, 256, 0, stream>>>(eix, E, flag, cnt_mat, NB);
    scan_bucket_kernel<<<NB, 256, 0, stream>>>(cnt_mat, btotal);
    scan_btotal_kernel<<<1, 512, 0, stream>>>(btotal, bbase, boff, NB, N, E, row_ptr);
    p2_scatter_kernel<<<PB, 256, 0, stream>>>(eix, E, flag, cnt_mat, bbase, bdata, NB);
    csr_build_kernel<<<NB, 256, 0, stream>>>(bdata, boff, N, row_ptr, csr_src);

    convert_x_kernel<<<2048, 256, 0, stream>>>(bufA, x, N * 32);
    pack_w_kernel<<<(7 * 2048 + 255) / 256, 256, 0, stream>>>(pk, W1, W2, l1W);

    const int gBlocks = 2048;
    const int mBlocks = (N + 127) / 128;

    __half* cur = bufA;
    __half* oth = bufB;
    for (int l = 0; l < 3; ++l) {
        gather_h_kernel<<<gBlocks, 256, 0, stream>>>(oth, cur, row_ptr, csr_src, eps, l, N);
        gemm12_h_kernel<<<mBlocks, 256, 0, stream>>>(
            oth,
            pk + (size_t)l * 16384, b1 + l * 128, g1 + l * 128, bb1 + l * 128,
            m1 + l * 128, v1 + l * 128,
            pk + (size_t)(3 + l) * 16384, b2 + l * 128, g2 + l * 128, bb2 + l * 128,
            m2 + l * 128, v2 + l * 128,
            oth, N);
        __half* t = cur; cur = oth; oth = t;
    }
    // fused lin1 + ReLU + lin2 + log_softmax
    lin1_head_kernel<<<mBlocks, 256, 0, stream>>>(
        cur, pk + (size_t)6 * 16384, l1b, l2W, l2b, (float*)d_out, N);
}

// Round 10
// 338.195 us; speedup vs baseline: 2.9879x; 1.0238x over previous
//
#include <hip/hip_runtime.h>
#include <hip/hip_fp16.h>

// GIN: 3 layers of {CSR-gather aggregate fused with (1+eps)*x, fused MLP(2x GEMM128 via
// MFMA, BN folded, ReLU)}, then fused lin1+ReLU+lin2+log_softmax head.
// N=100000, E=1.6M. Round 10: gather restructured -- 4x16-lane groups, uint4
// (16B/lane) row reads, 4 neighbor rows in flight per load round, cross-group
// shfl reduce. 4x fewer load instructions for the same bytes.

#define PB 256    // partition blocks
#define MAXNB 512 // max buckets (N <= 131072)

typedef _Float16 f16x8 __attribute__((ext_vector_type(8)));
typedef float f32x4 __attribute__((ext_vector_type(4)));

struct H4 { __half2 a, b; };   // 8B fp16 quad

// ---------------------------------------------------------------------------
// Detect whether edge_index is int64 (all high words zero) or int32.
__global__ void detect_idx_kernel(const unsigned int* __restrict__ w, long long nOdd,
                                  int* __restrict__ flag) {
    __shared__ int any;
    if (threadIdx.x == 0) any = 0;
    __syncthreads();
    for (long long i = threadIdx.x; i < nOdd; i += blockDim.x) {
        if (w[2 * i + 1] != 0u) { any = 1; break; }
    }
    __syncthreads();
    if (threadIdx.x == 0) *flag = (any == 0) ? 1 : 0;   // 1 => int64 layout
}

// ---------------------------------------------------------------------------
// Pass 1: per-block LDS histogram over 256-node buckets -> cnt_mat[bucket][block].
__global__ __launch_bounds__(256) void p1_hist_kernel(
    const void* __restrict__ idx, long long E, const int* __restrict__ flag,
    int* __restrict__ cnt_mat, int NB) {
    __shared__ int h[MAXNB];
    for (int i = threadIdx.x; i < MAXNB; i += 256) h[i] = 0;
    __syncthreads();
    const long long C = (E + PB - 1) / PB;
    const long long lo = (long long)blockIdx.x * C;
    long long hi = lo + C; if (hi > E) hi = E;
    if (*flag) {
        const long long* pd = (const long long*)idx + E;
        for (long long i = lo + threadIdx.x; i < hi; i += 256)
            atomicAdd(&h[((int)pd[i]) >> 8], 1);
    } else {
        const int* pd = (const int*)idx + E;
        for (long long i = lo + threadIdx.x; i < hi; i += 256)
            atomicAdd(&h[pd[i] >> 8], 1);
    }
    __syncthreads();
    for (int i = threadIdx.x; i < NB; i += 256)
        cnt_mat[i * PB + blockIdx.x] = h[i];
}

// ---------------------------------------------------------------------------
// Per-bucket exclusive scan over the PB block-counts (in place) + bucket total.
__global__ __launch_bounds__(256) void scan_bucket_kernel(
    int* __restrict__ cnt_mat, int* __restrict__ btotal) {
    int k = blockIdx.x, t = threadIdx.x;
    __shared__ int sh[PB];
    int c = cnt_mat[k * PB + t];
    sh[t] = c;
    __syncthreads();
    for (int off = 1; off < PB; off <<= 1) {
        int v = (t >= off) ? sh[t - off] : 0;
        __syncthreads();
        sh[t] += v;
        __syncthreads();
    }
    cnt_mat[k * PB + t] = sh[t] - c;        // exclusive within bucket
    if (t == PB - 1) btotal[k] = sh[t];
}

// ---------------------------------------------------------------------------
// Exclusive scan of bucket totals -> bbase, boff; row_ptr[N] = E.
__global__ __launch_bounds__(512) void scan_btotal_kernel(
    const int* __restrict__ btotal, int* __restrict__ bbase, int* __restrict__ boff,
    int NB, int N, long long E, int* __restrict__ row_ptr) {
    int t = threadIdx.x;
    __shared__ int sh[512];
    int c = (t < NB) ? btotal[t] : 0;
    sh[t] = c;
    __syncthreads();
    for (int off = 1; off < 512; off <<= 1) {
        int v = (t >= off) ? sh[t - off] : 0;
        __syncthreads();
        sh[t] += v;
        __syncthreads();
    }
    int excl = sh[t] - c;
    if (t < NB) { bbase[t] = excl; boff[t] = excl; }
    if (t == 0) { boff[NB] = (int)E; row_ptr[N] = (int)E; }
}

// ---------------------------------------------------------------------------
// Pass 2: re-read chunk, LDS cursors seeded with global dense offsets, scatter
// (src,dst) into bucket-grouped bdata. Zero global atomics.
__global__ __launch_bounds__(256) void p2_scatter_kernel(
    const void* __restrict__ idx, long long E, const int* __restrict__ flag,
    const int* __restrict__ cnt_mat, const int* __restrict__ bbase,
    uint2* __restrict__ bdata, int NB) {
    __shared__ int cur[MAXNB];
    int b = blockIdx.x;
    for (int i = threadIdx.x; i < NB; i += 256)
        cur[i] = cnt_mat[i * PB + b] + bbase[i];
    __syncthreads();
    const long long C = (E + PB - 1) / PB;
    const long long lo = (long long)b * C;
    long long hi = lo + C; if (hi > E) hi = E;
    if (*flag) {
        const long long* ps = (const long long*)idx;
        const long long* pd = ps + E;
        for (long long i = lo + threadIdx.x; i < hi; i += 256) {
            int s = (int)ps[i], d = (int)pd[i];
            int r = atomicAdd(&cur[d >> 8], 1);
            bdata[r] = make_uint2((unsigned)s, (unsigned)d);
        }
    } else {
        const int* ps = (const int*)idx;
        const int* pd = ps + E;
        for (long long i = lo + threadIdx.x; i < hi; i += 256) {
            int s = ps[i], d = pd[i];
            int r = atomicAdd(&cur[d >> 8], 1);
            bdata[r] = make_uint2((unsigned)s, (unsigned)d);
        }
    }
}

// ---------------------------------------------------------------------------
// Per-bucket CSR finalize (256 nodes/bucket): LDS hist, LDS scan, row_ptr write,
// then place src into csr_src (16KB window per bucket, L2-absorbed).
__global__ __launch_bounds__(256) void csr_build_kernel(
    const uint2* __restrict__ bdata, const int* __restrict__ boff, int N,
    int* __restrict__ row_ptr, int* __restrict__ csr_src) {
    int b = blockIdx.x, t = threadIdx.x;
    int lo = boff[b], hi = boff[b + 1];
    int nb = b << 8;
    __shared__ int cnt[256];
    __shared__ int sh[256];
    cnt[t] = 0;
    __syncthreads();
    for (int i = lo + t; i < hi; i += 256)
        atomicAdd(&cnt[bdata[i].y & 255], 1);
    __syncthreads();
    int c = cnt[t];
    sh[t] = c;
    __syncthreads();
    for (int off = 1; off < 256; off <<= 1) {
        int v = (t >= off) ? sh[t - off] : 0;
        __syncthreads();
        sh[t] += v;
        __syncthreads();
    }
    int excl = sh[t] - c;
    if (nb + t < N) row_ptr[nb + t] = lo + excl;
    cnt[t] = excl;                 // cursor: local absolute position
    __syncthreads();
    for (int i = lo + t; i < hi; i += 256) {
        uint2 e = bdata[i];
        int p = atomicAdd(&cnt[e.y & 255], 1);
        csr_src[lo + p] = (int)e.x;
    }
}

// ---------------------------------------------------------------------------
// x fp32 [N,128] -> fp16.
__global__ void convert_x_kernel(__half* __restrict__ out, const float* __restrict__ in,
                                 int n4) {
    int i = blockIdx.x * blockDim.x + threadIdx.x;
    int stride = gridDim.x * blockDim.x;
    const float4* in4 = (const float4*)in;
    for (; i < n4; i += stride) {
        float4 v = in4[i];
        H4 h;
        h.a = __float22half2_rn(make_float2(v.x, v.y));
        h.b = __float22half2_rn(make_float2(v.z, v.w));
        *(H4*)(out + i * 4) = h;
    }
}

// ---------------------------------------------------------------------------
// Pack 7 fp32 [128][128] weight matrices (W1 l0..2, W2 l0..2, lin1) into fp16
// MFMA "A-operand" fragment order: pk[mat][((ks*8+ct)*64+lane)*8 + j] =
//   W[ks*32 + (lane>>4)*8 + j][ct*16 + (lane&15)]
__global__ void pack_w_kernel(__half* __restrict__ pk, const float* __restrict__ W1,
                              const float* __restrict__ W2, const float* __restrict__ lin1) {
    int t = blockIdx.x * blockDim.x + threadIdx.x;
    if (t >= 7 * 2048) return;
    int mat = t >> 11;
    int rem = t & 2047;
    int ks = rem >> 9;
    int ct = (rem >> 6) & 7;
    int lane = rem & 63;
    int g = lane >> 4, c = lane & 15;
    const float* src = (mat < 3) ? W1 + mat * 16384
                     : (mat < 6) ? W2 + (mat - 3) * 16384
                                 : lin1;
    __half* dst = pk + mat * 16384 + ((size_t)((ks * 8 + ct) * 64 + lane)) * 8;
#pragma unroll
    for (int j = 0; j < 8; ++j)
        dst[j] = (__half)src[(ks * 32 + g * 8 + j) * 128 + ct * 16 + c];
}

// ---------------------------------------------------------------------------
// out[n] = fp16( (1+eps)*x[n] + sum_j x[csr[j]] ), fp32 accumulate.
// Wave = 4 groups x 16 lanes. Lane (g,t): reads 16B chunk t of every-4th
// neighbor row (4 rows in flight per round, unroll 2 -> 8). Cross-group
// shfl_xor(16|32) reduce; group 0 adds (1+eps)*self and stores uint4.
__global__ __launch_bounds__(256) void gather_h_kernel(
    __half* __restrict__ out, const __half* __restrict__ x,
    const int* __restrict__ row_ptr, const int* __restrict__ csr,
    const float* __restrict__ eps, int layer, int N) {
    int wave = threadIdx.x >> 6;
    int lane = threadIdx.x & 63;
    int g = lane >> 4;          // neighbor sub-group
    int t = lane & 15;          // 16B chunk within row
    int wid = blockIdx.x * 4 + wave;
    int nw = gridDim.x * 4;
    float s = 1.0f + eps[layer];
    for (int n = wid; n < N; n += nw) {
        int beg = row_ptr[n], end = row_ptr[n + 1];
        float2 a0 = make_float2(0.f, 0.f), a1 = a0, a2 = a0, a3 = a0;
#define ACC16(vv) { \
        float2 f0 = __half22float2(((const __half2*)&(vv))[0]); \
        float2 f1 = __half22float2(((const __half2*)&(vv))[1]); \
        float2 f2 = __half22float2(((const __half2*)&(vv))[2]); \
        float2 f3 = __half22float2(((const __half2*)&(vv))[3]); \
        a0.x += f0.x; a0.y += f0.y; a1.x += f1.x; a1.y += f1.y; \
        a2.x += f2.x; a2.y += f2.y; a3.x += f3.x; a3.y += f3.y; }
        int j = beg + g;
        for (; j + 4 < end; j += 8) {
            uint4 v0 = *(const uint4*)(x + (long long)csr[j] * 128 + t * 8);
            uint4 v1 = *(const uint4*)(x + (long long)csr[j + 4] * 128 + t * 8);
            ACC16(v0);
            ACC16(v1);
        }
        if (j < end) {
            uint4 v0 = *(const uint4*)(x + (long long)csr[j] * 128 + t * 8);
            ACC16(v0);
        }
#undef ACC16
        // reduce across the 4 groups (all lanes participate)
        a0.x += __shfl_xor(a0.x, 16); a0.y += __shfl_xor(a0.y, 16);
        a1.x += __shfl_xor(a1.x, 16); a1.y += __shfl_xor(a1.y, 16);
        a2.x += __shfl_xor(a2.x, 16); a2.y += __shfl_xor(a2.y, 16);
        a3.x += __shfl_xor(a3.x, 16); a3.y += __shfl_xor(a3.y, 16);
        a0.x += __shfl_xor(a0.x, 32); a0.y += __shfl_xor(a0.y, 32);
        a1.x += __shfl_xor(a1.x, 32); a1.y += __shfl_xor(a1.y, 32);
        a2.x += __shfl_xor(a2.x, 32); a2.y += __shfl_xor(a2.y, 32);
        a3.x += __shfl_xor(a3.x, 32); a3.y += __shfl_xor(a3.y, 32);
        if (g == 0) {
            uint4 sv = *(const uint4*)(x + (long long)n * 128 + t * 8);
            float2 f0 = __half22float2(((const __half2*)&sv)[0]);
            float2 f1 = __half22float2(((const __half2*)&sv)[1]);
            float2 f2 = __half22float2(((const __half2*)&sv)[2]);
            float2 f3 = __half22float2(((const __half2*)&sv)[3]);
            a0.x = fmaf(s, f0.x, a0.x); a0.y = fmaf(s, f0.y, a0.y);
            a1.x = fmaf(s, f1.x, a1.x); a1.y = fmaf(s, f1.y, a1.y);
            a2.x = fmaf(s, f2.x, a2.x); a2.y = fmaf(s, f2.y, a2.y);
            a3.x = fmaf(s, f3.x, a3.x); a3.y = fmaf(s, f3.y, a3.y);
            uint4 o;
            ((__half2*)&o)[0] = __float22half2_rn(a0);
            ((__half2*)&o)[1] = __float22half2_rn(a1);
            ((__half2*)&o)[2] = __float22half2_rn(a2);
            ((__half2*)&o)[3] = __float22half2_rn(a3);
            *(uint4*)(out + (long long)n * 128 + t * 8) = o;
        }
    }
}

// ---------------------------------------------------------------------------
// Fused MLP: out = relu(BN2(relu(BN1(in@W1+b1))@W2+b2)). 128 rows/block.
// GEMM1 epilogue writes fp16 h1 back into the SAME swizzled LDS tile (barrier-
// protected), GEMM2 consumes it. In-place safe.
__global__ __launch_bounds__(256) void gemm12_h_kernel(
    const __half* __restrict__ in,
    const __half* __restrict__ pk1, const float* __restrict__ b1,
    const float* __restrict__ g1, const float* __restrict__ bb1,
    const float* __restrict__ m1, const float* __restrict__ v1,
    const __half* __restrict__ pk2, const float* __restrict__ b2,
    const float* __restrict__ g2, const float* __restrict__ bb2,
    const float* __restrict__ m2, const float* __restrict__ v2,
    __half* __restrict__ out, int N) {
    __shared__ __half sA[128 * 128];
    __shared__ float sc1_s[128], sh1_s[128], sc2_s[128], sh2_s[128];

    const int tid = threadIdx.x;
    if (tid < 128) {
        int c = tid;
        float sc = g1[c] * rsqrtf(v1[c] + 1e-5f);
        sc1_s[c] = sc;
        sh1_s[c] = b1[c] * sc + bb1[c] - m1[c] * sc;
        sc = g2[c] * rsqrtf(v2[c] + 1e-5f);
        sc2_s[c] = sc;
        sh2_s[c] = b2[c] * sc + bb2[c] - m2[c] * sc;
    }

    const int base = blockIdx.x * 128;
#pragma unroll
    for (int q = 0; q < 8; ++q) {
        int i = tid + q * 256;
        int row = i >> 4, c = i & 15;
        int r = base + row;
        if (r >= N) r = N - 1;
        uint4 v = *(const uint4*)(in + r * 128 + c * 8);
        *(uint4*)&sA[row * 128 + ((c ^ (row & 15)) * 8)] = v;
    }
    __syncthreads();

    const int wave = tid >> 6;
    const int lane = tid & 63;
    const int g16 = lane >> 4;
    const int r15 = lane & 15;

    f32x4 acc[2][8];
#pragma unroll
    for (int rt = 0; rt < 2; ++rt)
#pragma unroll
        for (int ct = 0; ct < 8; ++ct) acc[rt][ct] = (f32x4)0.f;

    // ---- GEMM1 ----
#pragma unroll
    for (int ks = 0; ks < 4; ++ks) {
        f16x8 wf[8];
#pragma unroll
        for (int ct = 0; ct < 8; ++ct)
            wf[ct] = *(const f16x8*)(pk1 + ((ks * 8 + ct) * 64 + lane) * 8);
#pragma unroll
        for (int rt = 0; rt < 2; ++rt) {
            int row = wave * 32 + rt * 16 + r15;
            f16x8 bf = *(const f16x8*)&sA[row * 128 + (((ks * 4 + g16) ^ r15) * 8)];
#pragma unroll
            for (int ct = 0; ct < 8; ++ct)
                acc[rt][ct] = __builtin_amdgcn_mfma_f32_16x16x32_f16(wf[ct], bf,
                                                                     acc[rt][ct], 0, 0, 0);
        }
    }

    __syncthreads();   // all reads of sA done -> safe to overwrite
    // epilogue 1: BN1 + ReLU -> fp16 back into swizzled sA
#pragma unroll
    for (int rt = 0; rt < 2; ++rt) {
        int row = wave * 32 + rt * 16 + r15;
#pragma unroll
        for (int ct = 0; ct < 8; ++ct) {
            int col = ct * 16 + g16 * 4;
            float4 sc4 = *(float4*)&sc1_s[col];
            float4 sh4 = *(float4*)&sh1_s[col];
            f32x4 a = acc[rt][ct];
            float o0 = fmaxf(fmaf(a[0], sc4.x, sh4.x), 0.f);
            float o1 = fmaxf(fmaf(a[1], sc4.y, sh4.y), 0.f);
            float o2 = fmaxf(fmaf(a[2], sc4.z, sh4.z), 0.f);
            float o3 = fmaxf(fmaf(a[3], sc4.w, sh4.w), 0.f);
            H4 h;
            h.a = __float22half2_rn(make_float2(o0, o1));
            h.b = __float22half2_rn(make_float2(o2, o3));
            int c = col >> 3;
            *(H4*)&sA[row * 128 + ((c ^ (row & 15)) * 8) + (col & 7)] = h;
        }
    }
    __syncthreads();

    // ---- GEMM2 ----
#pragma unroll
    for (int rt = 0; rt < 2; ++rt)
#pragma unroll
        for (int ct = 0; ct < 8; ++ct) acc[rt][ct] = (f32x4)0.f;
#pragma unroll
    for (int ks = 0; ks < 4; ++ks) {
        f16x8 wf[8];
#pragma unroll
        for (int ct = 0; ct < 8; ++ct)
            wf[ct] = *(const f16x8*)(pk2 + ((ks * 8 + ct) * 64 + lane) * 8);
#pragma unroll
        for (int rt = 0; rt < 2; ++rt) {
            int row = wave * 32 + rt * 16 + r15;
            f16x8 bf = *(const f16x8*)&sA[row * 128 + (((ks * 4 + g16) ^ r15) * 8)];
#pragma unroll
            for (int ct = 0; ct < 8; ++ct)
                acc[rt][ct] = __builtin_amdgcn_mfma_f32_16x16x32_f16(wf[ct], bf,
                                                                     acc[rt][ct], 0, 0, 0);
        }
    }

    // epilogue 2: BN2 + ReLU -> global fp16
#pragma unroll
    for (int rt = 0; rt < 2; ++rt) {
        int r = base + wave * 32 + rt * 16 + r15;
        if (r < N) {
            __half* orow = out + r * 128;
#pragma unroll
            for (int ct = 0; ct < 8; ++ct) {
                int col = ct * 16 + g16 * 4;
                float4 sc4 = *(float4*)&sc2_s[col];
                float4 sh4 = *(float4*)&sh2_s[col];
                f32x4 a = acc[rt][ct];
                float o0 = fmaxf(fmaf(a[0], sc4.x, sh4.x), 0.f);
                float o1 = fmaxf(fmaf(a[1], sc4.y, sh4.y), 0.f);
                float o2 = fmaxf(fmaf(a[2], sc4.z, sh4.z), 0.f);
                float o3 = fmaxf(fmaf(a[3], sc4.w, sh4.w), 0.f);
                H4 h;
                h.a = __float22half2_rn(make_float2(o0, o1));
                h.b = __float22half2_rn(make_float2(o2, o3));
                *(H4*)(orow + col) = h;
            }
        }
    }
}

// ---------------------------------------------------------------------------
// Fused head: h = relu(in@lin1W+lin1b); logits = h@lin2W+lin2b; log_softmax.
__global__ __launch_bounds__(256) void lin1_head_kernel(
    const __half* __restrict__ in, const __half* __restrict__ pk1,
    const float* __restrict__ l1b, const float* __restrict__ l2W,
    const float* __restrict__ l2b, float* __restrict__ out, int N) {
    __shared__ __half sA[128 * 128];
    __shared__ float Wl[1280];
    __shared__ float bl[10];
    __shared__ float b1_s[128];

    const int tid = threadIdx.x;
    for (int i = tid; i < 1280; i += 256) Wl[i] = l2W[i];
    if (tid < 10) bl[tid] = l2b[tid];
    if (tid < 128) b1_s[tid] = l1b[tid];

    const int base = blockIdx.x * 128;
#pragma unroll
    for (int q = 0; q < 8; ++q) {
        int i = tid + q * 256;
        int row = i >> 4, c = i & 15;
        int r = base + row;
        if (r >= N) r = N - 1;
        uint4 v = *(const uint4*)(in + r * 128 + c * 8);
        *(uint4*)&sA[row * 128 + ((c ^ (row & 15)) * 8)] = v;
    }
    __syncthreads();

    const int wave = tid >> 6;
    const int lane = tid & 63;
    const int g16 = lane >> 4;
    const int r15 = lane & 15;

    f32x4 acc[2][8];
#pragma unroll
    for (int rt = 0; rt < 2; ++rt)
#pragma unroll
        for (int ct = 0; ct < 8; ++ct) acc[rt][ct] = (f32x4)0.f;

#pragma unroll
    for (int ks = 0; ks < 4; ++ks) {
        f16x8 wf[8];
#pragma unroll
        for (int ct = 0; ct < 8; ++ct)
            wf[ct] = *(const f16x8*)(pk1 + ((ks * 8 + ct) * 64 + lane) * 8);
#pragma unroll
        for (int rt = 0; rt < 2; ++rt) {
            int row = wave * 32 + rt * 16 + r15;
            f16x8 bf = *(const f16x8*)&sA[row * 128 + (((ks * 4 + g16) ^ r15) * 8)];
#pragma unroll
            for (int ct = 0; ct < 8; ++ct)
                acc[rt][ct] = __builtin_amdgcn_mfma_f32_16x16x32_f16(wf[ct], bf,
                                                                     acc[rt][ct], 0, 0, 0);
        }
    }

#pragma unroll
    for (int rt = 0; rt < 2; ++rt) {
        float p[10];
#pragma unroll
        for (int c = 0; c < 10; ++c) p[c] = 0.f;
#pragma unroll
        for (int ct = 0; ct < 8; ++ct) {
            int col0 = ct * 16 + g16 * 4;
#pragma unroll
            for (int j = 0; j < 4; ++j) {
                int col = col0 + j;
                float h = fmaxf(acc[rt][ct][j] + b1_s[col], 0.f);
#pragma unroll
                for (int c = 0; c < 10; ++c) p[c] = fmaf(h, Wl[col * 10 + c], p[c]);
            }
        }
#pragma unroll
        for (int c = 0; c < 10; ++c) {
            p[c] += __shfl_xor(p[c], 16);
            p[c] += __shfl_xor(p[c], 32);
        }
        int r = base + wave * 32 + rt * 16 + r15;
        if (g16 == 0 && r < N) {
            float mx = -1e30f;
#pragma unroll
            for (int c = 0; c < 10; ++c) {
                p[c] += bl[c];
                mx = fmaxf(mx, p[c]);
            }
            float sum = 0.f;
#pragma unroll
            for (int c = 0; c < 10; ++c) sum += expf(p[c] - mx);
            float lse = mx + logf(sum);
            float* orow = out + (long long)r * 10;
#pragma unroll
            for (int c = 0; c < 10; ++c) orow[c] = p[c] - lse;
        }
    }
}

// ---------------------------------------------------------------------------
extern "C" void kernel_launch(void* const* d_in, const int* in_sizes, int n_in,
                              void* d_out, int out_size, void* d_ws, size_t ws_size,
                              hipStream_t stream) {
    const float* x   = (const float*)d_in[0];
    const void*  eix = d_in[1];
    const float* eps = (const float*)d_in[2];
    const float* W1  = (const float*)d_in[3];
    const float* b1  = (const float*)d_in[4];
    const float* g1  = (const float*)d_in[5];
    const float* bb1 = (const float*)d_in[6];
    const float* m1  = (const float*)d_in[7];
    const float* v1  = (const float*)d_in[8];
    const float* W2  = (const float*)d_in[9];
    const float* b2  = (const float*)d_in[10];
    const float* g2  = (const float*)d_in[11];
    const float* bb2 = (const float*)d_in[12];
    const float* m2  = (const float*)d_in[13];
    const float* v2  = (const float*)d_in[14];
    const float* l1W = (const float*)d_in[15];
    const float* l1b = (const float*)d_in[16];
    const float* l2W = (const float*)d_in[17];
    const float* l2b = (const float*)d_in[18];

    const int N = in_sizes[0] / 128;
    const long long E = in_sizes[1] / 2;
    const int NB = (N + 255) >> 8;            // 256-node buckets (<=512)

    // workspace layout (16B-aligned blocks first)
    __half* bufA  = (__half*)d_ws;                     // N*128 fp16
    __half* bufB  = bufA + (size_t)N * 128;            // N*128 fp16
    __half* pk    = bufB + (size_t)N * 128;            // 7*16384 fp16
    uint2*  bdata = (uint2*)(pk + 7 * 16384);          // E pairs (8B)
    int* csr_src  = (int*)(bdata + E);                 // E
    int* row_ptr  = csr_src + E;                       // N+1
    int* cnt_mat  = row_ptr + N + 1;                   // MAXNB*PB
    int* btotal   = cnt_mat + MAXNB * PB;              // MAXNB
    int* bbase    = btotal + MAXNB;                    // MAXNB
    int* boff     = bbase + MAXNB;                     // MAXNB+1
    int* flag     = boff + MAXNB + 1;                  // 1

    detect_idx_kernel<<<1, 256, 0, stream>>>((const unsigned int*)eix,
                                             (E < 2048 ? E : 2048), flag);

    p1_hist_kernel<<<PB, 256, 0, stream>>>(eix, E, flag, cnt_mat, NB);
    scan_bucket_kernel<<<NB, 256, 0, stream>>>(cnt_mat, btotal);
    scan_btotal_kernel<<<1, 512, 0, stream>>>(btotal, bbase, boff, NB, N, E, row_ptr);
    p2_scatter_kernel<<<PB, 256, 0, stream>>>(eix, E, flag, cnt_mat, bbase, bdata, NB);
    csr_build_kernel<<<NB, 256, 0, stream>>>(bdata, boff, N, row_ptr, csr_src);

    convert_x_kernel<<<2048, 256, 0, stream>>>(bufA, x, N * 32);
    pack_w_kernel<<<(7 * 2048 + 255) / 256, 256, 0, stream>>>(pk, W1, W2, l1W);

    const int gBlocks = 2048;
    const int mBlocks = (N + 127) / 128;

    __half* cur = bufA;
    __half* oth = bufB;
    for (int l = 0; l < 3; ++l) {
        gather_h_kernel<<<gBlocks, 256, 0, stream>>>(oth, cur, row_ptr, csr_src, eps, l, N);
        gemm12_h_kernel<<<mBlocks, 256, 0, stream>>>(
            oth,
            pk + (size_t)l * 16384, b1 + l * 128, g1 + l * 128, bb1 + l * 128,
            m1 + l * 128, v1 + l * 128,
            pk + (size_t)(3 + l) * 16384, b2 + l * 128, g2 + l * 128, bb2 + l * 128,
            m2 + l * 128, v2 + l * 128,
            oth, N);
        __half* t = cur; cur = oth; oth = t;
    }
    // fused lin1 + ReLU + lin2 + log_softmax
    lin1_head_kernel<<<mBlocks, 256, 0, stream>>>(
        cur, pk + (size_t)6 * 16384, l1b, l2W, l2b, (float*)d_out, N);
}